// Round 4
// baseline (192.136 us; speedup 1.0000x reference)
//
#include <hip/hip_runtime.h>
#include <hip/hip_bf16.h>
#include <math.h>

// Problem constants
#define GH 64
#define GW 64
#define CC 384
#define NHD 6
#define KW 7
#define DH 64
#define NTOK (GH*GW)          // 4096
#define LN_EPS 1e-6f

typedef __attribute__((ext_vector_type(4))) float f32x4;
typedef __attribute__((ext_vector_type(8))) short bf16x8;
typedef __hip_bfloat16 bf16;

__device__ __forceinline__ float bf2f(unsigned int u16) {
    union { unsigned int i; float f; } c; c.i = u16 << 16; return c.f;
}
__device__ __forceinline__ bf16 f2bf(float f) { return __float2bfloat16(f); }

// ---------------------------------------------------------------------------
// Kernel 1: fused {4 weight transposes} + {ada modulation} in ONE dispatch.
// blocks 0..1727: out[n][k]=bf16(in[k][n]) 32x32 tiles
//   qkv 432 | proj 144 | fc1 576 | fc2 576
// blocks 1728..1763: m = silu(cond) @ ada_w + ada_b (64 cols each)
// ---------------------------------------------------------------------------
__global__ __launch_bounds__(256) void wt_ada_k(const float* __restrict__ qkv_w,
                                                const float* __restrict__ proj_w,
                                                const float* __restrict__ fc1_w,
                                                const float* __restrict__ fc2_w,
                                                bf16* __restrict__ qkv_wt,
                                                bf16* __restrict__ proj_wt,
                                                bf16* __restrict__ fc1_wt,
                                                bf16* __restrict__ fc2_wt,
                                                const float* __restrict__ cond,
                                                const float* __restrict__ aw,
                                                const float* __restrict__ ab,
                                                float* __restrict__ m)
{
    int b = blockIdx.x;
    int tid = threadIdx.x;
    if (b >= 1728) {
        // ---- ada part ----
        __shared__ float s[CC];
        __shared__ float red[4][64];
        for (int i = tid; i < CC; i += 256) {
            float c = cond[i];
            s[i] = c / (1.f + expf(-c));
        }
        __syncthreads();
        int c  = tid & 63;
        int ks = tid >> 6;
        int col = (b - 1728) * 64 + c;
        float acc = 0.f;
        for (int k = ks * 96; k < (ks + 1) * 96; ++k)
            acc += s[k] * aw[(size_t)k * (6*CC) + col];
        red[ks][c] = acc;
        __syncthreads();
        if (tid < 64)
            m[col] = red[0][c] + red[1][c] + red[2][c] + red[3][c] + ab[col];
        return;
    }
    // ---- transpose part ----
    __shared__ float t[32][33];
    const float* in; bf16* outp; int K, N, lid;
    if (b < 432)       { in = qkv_w;  outp = qkv_wt;  K = 384;  N = 1152; lid = b; }
    else if (b < 576)  { in = proj_w; outp = proj_wt; K = 384;  N = 384;  lid = b - 432; }
    else if (b < 1152) { in = fc1_w;  outp = fc1_wt;  K = 384;  N = 1536; lid = b - 576; }
    else               { in = fc2_w;  outp = fc2_wt;  K = 1536; N = 384;  lid = b - 1152; }
    int nbn = N / 32;
    int bn = (lid % nbn) * 32, bk = (lid / nbn) * 32;
    int x = tid & 31, y = tid >> 5;   // (32,8)
    #pragma unroll
    for (int i = 0; i < 32; i += 8)
        t[y + i][x] = in[(size_t)(bk + y + i) * N + bn + x];
    __syncthreads();
    #pragma unroll
    for (int i = 0; i < 32; i += 8)
        outp[(size_t)(bn + y + i) * K + bk + x] = f2bf(t[x][y + i]);
}

// ---------------------------------------------------------------------------
// Kernel 2: y = LN(x) * (1 + sc) + sh   -> bf16   (one block of 128 per token)
// ---------------------------------------------------------------------------
__global__ __launch_bounds__(128) void ln_mod_k(const float* __restrict__ xin,
                                                const float* __restrict__ sh,
                                                const float* __restrict__ sc,
                                                bf16* __restrict__ yout)
{
    int t = blockIdx.x;
    int tid = threadIdx.x;
    const float* xr = xin + (size_t)t * CC;
    float v0 = xr[tid], v1 = xr[tid + 128], v2 = xr[tid + 256];
    float s  = v0 + v1 + v2;
    float ss = v0*v0 + v1*v1 + v2*v2;
    #pragma unroll
    for (int off = 32; off; off >>= 1) {
        s  += __shfl_down(s,  off);
        ss += __shfl_down(ss, off);
    }
    __shared__ float red[4];
    int wid = tid >> 6;
    if ((tid & 63) == 0) { red[wid*2] = s; red[wid*2+1] = ss; }
    __syncthreads();
    s  = red[0] + red[2];
    ss = red[1] + red[3];
    float mean = s * (1.f / CC);
    float var  = ss * (1.f / CC) - mean * mean;
    float rstd = rsqrtf(var + LN_EPS);
    bf16* yr = yout + (size_t)t * CC;
    yr[tid      ] = f2bf((v0 - mean) * rstd * (1.f + sc[tid      ]) + sh[tid      ]);
    yr[tid + 128] = f2bf((v1 - mean) * rstd * (1.f + sc[tid + 128]) + sh[tid + 128]);
    yr[tid + 256] = f2bf((v2 - mean) * rstd * (1.f + sc[tid + 256]) + sh[tid + 256]);
}

// ---------------------------------------------------------------------------
// Kernel 3: MFMA bf16 GEMM, 2-phase double-buffered (reg-prefetch next tile).
// out[M,N] = A[M,K] @ Bt[N,K]^T + epilogue.  BK=64, 256 threads = 4 waves 2x2,
// wave tile (BM/2)x(BN/2); FM=BM/32, FN=BN/32 fragments.
// EPI: 0 = +bias (bf16) ; 1 = resid + g*(+bias) (f32) ; 2 = gelu(+bias) (bf16)
// ---------------------------------------------------------------------------
#define GBK 64
#define LDKP 72   // padded K stride (bf16): 144B rows -> ~2-way conflicts (free)

template<int EPI, typename OutT, int BM, int BN>
__global__ __launch_bounds__(256) void mgemm_k(const bf16* __restrict__ A,   // [M][K]
                                               const bf16* __restrict__ Bt,  // [N][K]
                                               const float* __restrict__ bias,
                                               const float* __restrict__ resid,
                                               const float* __restrict__ gvec,
                                               OutT* __restrict__ out,
                                               int M, int N, int Kd)
{
    constexpr int FM = BM / 32, FN = BN / 32;
    constexpr int AV = BM / 32, BV = BN / 32;   // uint4 loads per thread
    __shared__ bf16 As[2][BM][LDKP];
    __shared__ bf16 Bs[2][BN][LDKP];
    int tid = threadIdx.x;
    int wid = tid >> 6, lane = tid & 63;
    int wm = wid >> 1, wn = wid & 1;
    int row_base = blockIdx.y * BM;
    int col_base = blockIdx.x * BN;

    int r_st = tid >> 3;           // 0..31
    int kc   = (tid & 7) * 8;      // 0..56

    uint4 ra[AV], rb[BV];
    f32x4 acc[FM][FN] = {};

    const int nt = Kd / GBK;

    // prologue: tile 0
    #pragma unroll
    for (int i = 0; i < AV; ++i)
        ra[i] = *(const uint4*)&A [(size_t)(row_base + r_st + i*32) * Kd + kc];
    #pragma unroll
    for (int i = 0; i < BV; ++i)
        rb[i] = *(const uint4*)&Bt[(size_t)(col_base + r_st + i*32) * Kd + kc];
    #pragma unroll
    for (int i = 0; i < AV; ++i) *(uint4*)&As[0][r_st + i*32][kc] = ra[i];
    #pragma unroll
    for (int i = 0; i < BV; ++i) *(uint4*)&Bs[0][r_st + i*32][kc] = rb[i];
    __syncthreads();

    for (int t = 0; t < nt; ++t) {
        int cur = t & 1;
        // issue prefetch of tile t+1 (global -> regs), latency hides under MFMAs
        if (t + 1 < nt) {
            int k0 = (t + 1) * GBK;
            #pragma unroll
            for (int i = 0; i < AV; ++i)
                ra[i] = *(const uint4*)&A [(size_t)(row_base + r_st + i*32) * Kd + k0 + kc];
            #pragma unroll
            for (int i = 0; i < BV; ++i)
                rb[i] = *(const uint4*)&Bt[(size_t)(col_base + r_st + i*32) * Kd + k0 + kc];
        }
        // compute current tile
        #pragma unroll
        for (int kk = 0; kk < GBK; kk += 32) {
            bf16x8 af[FM], bfr[FN];
            #pragma unroll
            for (int m = 0; m < FM; ++m)
                af[m]  = *(const bf16x8*)&As[cur][wm*(BM/2) + m*16 + (lane & 15)][kk + (lane >> 4) * 8];
            #pragma unroll
            for (int n = 0; n < FN; ++n)
                bfr[n] = *(const bf16x8*)&Bs[cur][wn*(BN/2) + n*16 + (lane & 15)][kk + (lane >> 4) * 8];
            #pragma unroll
            for (int m = 0; m < FM; ++m)
                #pragma unroll
                for (int n = 0; n < FN; ++n)
                    acc[m][n] = __builtin_amdgcn_mfma_f32_16x16x32_bf16(af[m], bfr[n], acc[m][n], 0, 0, 0);
        }
        // write prefetched tile into the other buffer
        if (t + 1 < nt) {
            int nxt = cur ^ 1;
            #pragma unroll
            for (int i = 0; i < AV; ++i) *(uint4*)&As[nxt][r_st + i*32][kc] = ra[i];
            #pragma unroll
            for (int i = 0; i < BV; ++i) *(uint4*)&Bs[nxt][r_st + i*32][kc] = rb[i];
        }
        __syncthreads();
    }

    // epilogue: C/D layout col=lane&15, row=(lane>>4)*4+reg
    int cl = lane & 15, rq = lane >> 4;
    #pragma unroll
    for (int m = 0; m < FM; ++m) {
        #pragma unroll
        for (int n = 0; n < FN; ++n) {
            int col = col_base + wn*(BN/2) + n*16 + cl;
            float bv = bias[col];
            float gv = (EPI == 1) ? gvec[col] : 0.f;
            #pragma unroll
            for (int j = 0; j < 4; ++j) {
                int row = row_base + wm*(BM/2) + m*16 + rq*4 + j;
                float v = acc[m][n][j] + bv;
                size_t idx = (size_t)row * N + col;
                if constexpr (EPI == 0) {
                    out[idx] = (OutT)f2bf(v);
                } else if constexpr (EPI == 1) {
                    out[idx] = resid[idx] + gv * v;
                } else { // gelu (tanh approx)
                    float u = 0.7978845608028654f * (v + 0.044715f * v * v * v);
                    out[idx] = (OutT)f2bf(0.5f * v * (1.f + tanhf(u)));
                }
            }
        }
    }
}

// ---------------------------------------------------------------------------
// Kernel 4: NATTEN 7x7 clamped-window attention (bf16 qkv -> bf16 out)
// One wave per (token, head). qkv layout: [tok][q(384) k(384) v(384)]
// ---------------------------------------------------------------------------
__global__ __launch_bounds__(256) void natten_k(const bf16* __restrict__ qkv,
                                                bf16* __restrict__ o)
{
    __shared__ float qs[4][DH];
    __shared__ float ps[4][64];
    int tid  = threadIdx.x;
    int w    = tid >> 6;
    int lane = tid & 63;
    int gw   = blockIdx.x * 4 + w;
    int head = gw % NHD;
    int token = gw / NHD;
    int hrow = token >> 6, wcol = token & 63;
    int sh = min(max(hrow - 3, 0), GH - KW);
    int sw = min(max(wcol - 3, 0), GW - KW);

    qs[w][lane] = __bfloat162float(qkv[(size_t)token * (3*CC) + head * DH + lane]) * 0.125f;
    __syncthreads();

    float score = -INFINITY;
    if (lane < KW*KW) {
        int jr = lane / KW, jc = lane % KW;
        int ntok = (sh + jr) * GW + (sw + jc);
        const uint4* kp = (const uint4*)(qkv + (size_t)ntok * (3*CC) + CC + head * DH);
        const float* qp = qs[w];
        float acc = 0.f;
        #pragma unroll
        for (int i = 0; i < 8; ++i) {
            uint4 kv = kp[i];
            acc += qp[i*8+0] * bf2f(kv.x & 0xffffu) + qp[i*8+1] * bf2f(kv.x >> 16)
                 + qp[i*8+2] * bf2f(kv.y & 0xffffu) + qp[i*8+3] * bf2f(kv.y >> 16)
                 + qp[i*8+4] * bf2f(kv.z & 0xffffu) + qp[i*8+5] * bf2f(kv.z >> 16)
                 + qp[i*8+6] * bf2f(kv.w & 0xffffu) + qp[i*8+7] * bf2f(kv.w >> 16);
        }
        score = acc;
    }
    float mx = score;
    #pragma unroll
    for (int off = 32; off; off >>= 1) mx = fmaxf(mx, __shfl_xor(mx, off));
    float p = (lane < KW*KW) ? expf(score - mx) : 0.f;
    float sm = p;
    #pragma unroll
    for (int off = 32; off; off >>= 1) sm += __shfl_xor(sm, off);
    p /= sm;
    ps[w][lane] = p;
    __syncthreads();

    float od = 0.f;
    #pragma unroll 7
    for (int j = 0; j < KW*KW; ++j) {
        int jr = j / KW, jc = j % KW;
        int ntok = (sh + jr) * GW + (sw + jc);
        od += ps[w][j] * __bfloat162float(qkv[(size_t)ntok * (3*CC) + 2*CC + head * DH + lane]);
    }
    o[(size_t)token * CC + head * DH + lane] = f2bf(od);
}

// ---------------------------------------------------------------------------
// launch
// ---------------------------------------------------------------------------
extern "C" void kernel_launch(void* const* d_in, const int* in_sizes, int n_in,
                              void* d_out, int out_size, void* d_ws, size_t ws_size,
                              hipStream_t stream)
{
    const float* x      = (const float*)d_in[0];
    const float* cond   = (const float*)d_in[1];
    const float* qkv_w  = (const float*)d_in[2];
    const float* qkv_b  = (const float*)d_in[3];
    const float* proj_w = (const float*)d_in[4];
    const float* proj_b = (const float*)d_in[5];
    const float* fc1_w  = (const float*)d_in[6];
    const float* fc1_b  = (const float*)d_in[7];
    const float* fc2_w  = (const float*)d_in[8];
    const float* fc2_b  = (const float*)d_in[9];
    const float* ada_w  = (const float*)d_in[10];
    const float* ada_b  = (const float*)d_in[11];
    float* out = (float*)d_out;

    // scratch layout (bytes)
    char* p = (char*)d_ws;
    float* m       = (float*)p;            p += 6*CC*sizeof(float);
    bf16* y        = (bf16*)p;             p += (size_t)NTOK*CC*2;
    bf16* qkv      = (bf16*)p;             p += (size_t)NTOK*(3*CC)*2;
    bf16* attn_o   = (bf16*)p;             p += (size_t)NTOK*CC*2;
    bf16* hdn      = (bf16*)p;             p += (size_t)NTOK*(4*CC)*2;
    bf16* qkv_wt   = (bf16*)p;             p += (size_t)(3*CC)*CC*2;
    bf16* proj_wt  = (bf16*)p;             p += (size_t)CC*CC*2;
    bf16* fc1_wt   = (bf16*)p;             p += (size_t)(4*CC)*CC*2;
    bf16* fc2_wt   = (bf16*)p;             p += (size_t)CC*(4*CC)*2;

    const float* sh_a = m;
    const float* sc_a = m + CC;
    const float* g_a  = m + 2*CC;
    const float* sh_m = m + 3*CC;
    const float* sc_m = m + 4*CC;
    const float* g_m  = m + 5*CC;

    // 0. weight transposes + ada modulation, one dispatch (1728 + 36 blocks)
    wt_ada_k<<<1764, 256, 0, stream>>>(qkv_w, proj_w, fc1_w, fc2_w,
                                       qkv_wt, proj_wt, fc1_wt, fc2_wt,
                                       cond, ada_w, ada_b, m);
    // 1. y = LN(x)*(1+sc_a)+sh_a
    ln_mod_k<<<NTOK, 128, 0, stream>>>(x, sh_a, sc_a, y);
    // 2. qkv = y @ qkv_w + qkv_b   (bf16 out)  grid (12,64)=768
    mgemm_k<0, bf16, 64, 96><<<dim3((3*CC)/96, NTOK/64), 256, 0, stream>>>(
        y, qkv_wt, qkv_b, nullptr, nullptr, qkv, NTOK, 3*CC, CC);
    // 3. neighborhood attention
    natten_k<<<(NTOK*NHD)/4, 256, 0, stream>>>(qkv, attn_o);
    // 4. x1 = x + g_a * (attn_o @ proj_w + proj_b) -> d_out (f32)  grid (6,128)=768
    mgemm_k<1, float, 32, 64><<<dim3(CC/64, NTOK/32), 256, 0, stream>>>(
        attn_o, proj_wt, proj_b, x, g_a, out, NTOK, CC, CC);
    // 5. y = LN(x1)*(1+sc_m)+sh_m
    ln_mod_k<<<NTOK, 128, 0, stream>>>(out, sh_m, sc_m, y);
    // 6. hdn = gelu(y @ fc1_w + fc1_b)  (bf16 out)  grid (16,64)=1024
    mgemm_k<2, bf16, 64, 96><<<dim3((4*CC)/96, NTOK/64), 256, 0, stream>>>(
        y, fc1_wt, fc1_b, nullptr, nullptr, hdn, NTOK, 4*CC, CC);
    // 7. out = x1 + g_m * (hdn @ fc2_w + fc2_b)  (in-place, f32)  grid (6,128)=768
    mgemm_k<1, float, 32, 64><<<dim3(CC/64, NTOK/32), 256, 0, stream>>>(
        hdn, fc2_wt, fc2_b, out, g_m, out, NTOK, CC, 4*CC);
}

// Round 5
// 111.487 us; speedup vs baseline: 1.7234x; 1.7234x over previous
//
#include <hip/hip_runtime.h>
#include <hip/hip_bf16.h>
#include <math.h>

// Problem constants
#define GH 64
#define GW 64
#define CC 384
#define NHD 6
#define KW 7
#define DH 64
#define NTOK (GH*GW)          // 4096
#define LN_EPS 1e-6f

typedef __attribute__((ext_vector_type(4))) float f32x4;
typedef __attribute__((ext_vector_type(8))) short bf16x8;
typedef __hip_bfloat16 bf16;

typedef const __attribute__((address_space(1))) unsigned int* gptr_t;
typedef __attribute__((address_space(3))) unsigned int* lptr_t;

__device__ __forceinline__ float bf2f(unsigned int u16) {
    union { unsigned int i; float f; } c; c.i = u16 << 16; return c.f;
}
__device__ __forceinline__ bf16 f2bf(float f) { return __float2bfloat16(f); }

// ---------------------------------------------------------------------------
// Kernel 1: fused {4 weight transposes} + {ada modulation} in ONE dispatch.
// blocks 0..1727: out[n][k]=bf16(in[k][n]) 32x32 tiles
// blocks 1728..1763: m = silu(cond) @ ada_w + ada_b (64 cols each)
// ---------------------------------------------------------------------------
__global__ __launch_bounds__(256) void wt_ada_k(const float* __restrict__ qkv_w,
                                                const float* __restrict__ proj_w,
                                                const float* __restrict__ fc1_w,
                                                const float* __restrict__ fc2_w,
                                                bf16* __restrict__ qkv_wt,
                                                bf16* __restrict__ proj_wt,
                                                bf16* __restrict__ fc1_wt,
                                                bf16* __restrict__ fc2_wt,
                                                const float* __restrict__ cond,
                                                const float* __restrict__ aw,
                                                const float* __restrict__ ab,
                                                float* __restrict__ m)
{
    int b = blockIdx.x;
    int tid = threadIdx.x;
    if (b >= 1728) {
        __shared__ float s[CC];
        __shared__ float red[4][64];
        for (int i = tid; i < CC; i += 256) {
            float c = cond[i];
            s[i] = c / (1.f + expf(-c));
        }
        __syncthreads();
        int c  = tid & 63;
        int ks = tid >> 6;
        int col = (b - 1728) * 64 + c;
        float acc = 0.f;
        for (int k = ks * 96; k < (ks + 1) * 96; ++k)
            acc += s[k] * aw[(size_t)k * (6*CC) + col];
        red[ks][c] = acc;
        __syncthreads();
        if (tid < 64)
            m[col] = red[0][c] + red[1][c] + red[2][c] + red[3][c] + ab[col];
        return;
    }
    __shared__ float t[32][33];
    const float* in; bf16* outp; int K, N, lid;
    if (b < 432)       { in = qkv_w;  outp = qkv_wt;  K = 384;  N = 1152; lid = b; }
    else if (b < 576)  { in = proj_w; outp = proj_wt; K = 384;  N = 384;  lid = b - 432; }
    else if (b < 1152) { in = fc1_w;  outp = fc1_wt;  K = 384;  N = 1536; lid = b - 576; }
    else               { in = fc2_w;  outp = fc2_wt;  K = 1536; N = 384;  lid = b - 1152; }
    int nbn = N / 32;
    int bn = (lid % nbn) * 32, bk = (lid / nbn) * 32;
    int x = tid & 31, y = tid >> 5;   // (32,8)
    #pragma unroll
    for (int i = 0; i < 32; i += 8)
        t[y + i][x] = in[(size_t)(bk + y + i) * N + bn + x];
    __syncthreads();
    #pragma unroll
    for (int i = 0; i < 32; i += 8)
        outp[(size_t)(bn + y + i) * K + bk + x] = f2bf(t[x][y + i]);
}

// ---------------------------------------------------------------------------
// Kernel 2: y = LN(x) * (1 + sc) + sh   -> bf16   (one block of 128 per token)
// ---------------------------------------------------------------------------
__global__ __launch_bounds__(128) void ln_mod_k(const float* __restrict__ xin,
                                                const float* __restrict__ sh,
                                                const float* __restrict__ sc,
                                                bf16* __restrict__ yout)
{
    int t = blockIdx.x;
    int tid = threadIdx.x;
    const float* xr = xin + (size_t)t * CC;
    float v0 = xr[tid], v1 = xr[tid + 128], v2 = xr[tid + 256];
    float s  = v0 + v1 + v2;
    float ss = v0*v0 + v1*v1 + v2*v2;
    #pragma unroll
    for (int off = 32; off; off >>= 1) {
        s  += __shfl_down(s,  off);
        ss += __shfl_down(ss, off);
    }
    __shared__ float red[4];
    int wid = tid >> 6;
    if ((tid & 63) == 0) { red[wid*2] = s; red[wid*2+1] = ss; }
    __syncthreads();
    s  = red[0] + red[2];
    ss = red[1] + red[3];
    float mean = s * (1.f / CC);
    float var  = ss * (1.f / CC) - mean * mean;
    float rstd = rsqrtf(var + LN_EPS);
    bf16* yr = yout + (size_t)t * CC;
    yr[tid      ] = f2bf((v0 - mean) * rstd * (1.f + sc[tid      ]) + sh[tid      ]);
    yr[tid + 128] = f2bf((v1 - mean) * rstd * (1.f + sc[tid + 128]) + sh[tid + 128]);
    yr[tid + 256] = f2bf((v2 - mean) * rstd * (1.f + sc[tid + 256]) + sh[tid + 256]);
}

// ---------------------------------------------------------------------------
// Kernel 3: MFMA bf16 GEMM, m97-style: global_load_lds(16B) staging,
// single-buffer, XOR-swizzled LDS (linear dest + pre-swizzled global source +
// swizzled ds_read).  out[M,N] = A[M,K] @ Bt[N,K]^T + epilogue.
// BK=64 (128B/row), 256 threads = 4 waves (2x2), wave tile (BM/2)x(BN/2).
// EPI: 0 = +bias (bf16) ; 1 = resid + g*(+bias) (f32) ; 2 = gelu(+bias) (bf16)
// ---------------------------------------------------------------------------
#define GBK 64

template<int EPI, typename OutT, int BM, int BN>
__global__ __launch_bounds__(256) void mgemm_k(const bf16* __restrict__ A,   // [M][K]
                                               const bf16* __restrict__ Bt,  // [N][K]
                                               const float* __restrict__ bias,
                                               const float* __restrict__ resid,
                                               const float* __restrict__ gvec,
                                               OutT* __restrict__ out,
                                               int M, int N, int Kd)
{
    constexpr int FM = BM / 32, FN = BN / 32;
    __shared__ __align__(16) bf16 As[BM][GBK];
    __shared__ __align__(16) bf16 Bs[BN][GBK];
    int tid = threadIdx.x;
    int wid = tid >> 6, lane = tid & 63;
    int wm = wid >> 1, wn = wid & 1;

    // XCD-aware bijective block swizzle (all grids used are divisible by 8)
    int gx = gridDim.x;
    int nwg = gx * gridDim.y;
    int bid = blockIdx.y * gx + blockIdx.x;
    int swz = (bid & 7) * (nwg >> 3) + (bid >> 3);
    int bx = swz % gx, by = swz / gx;

    int row_base = by * BM;
    int col_base = bx * BN;

    int l8 = lane >> 3;
    int cs = ((lane & 7) ^ l8) * 8;     // pre-swizzled global k-chunk (elements)
    int xr = (lane & 7) << 4;           // read-side XOR (bytes)
    int bcol = (lane >> 4) * 16;        // read-side k-byte base

    f32x4 acc[FM][FN] = {};

    for (int k0 = 0; k0 < Kd; k0 += GBK) {
        #pragma unroll
        for (int p = 0; p < BM / 32; ++p) {
            int rb = p * 32 + wid * 8;
            __builtin_amdgcn_global_load_lds(
                (gptr_t)(const void*)(A + (size_t)(row_base + rb + l8) * Kd + k0 + cs),
                (lptr_t)(void*)&As[rb][0], 16, 0, 0);
        }
        #pragma unroll
        for (int p = 0; p < BN / 32; ++p) {
            int rb = p * 32 + wid * 8;
            __builtin_amdgcn_global_load_lds(
                (gptr_t)(const void*)(Bt + (size_t)(col_base + rb + l8) * Kd + k0 + cs),
                (lptr_t)(void*)&Bs[rb][0], 16, 0, 0);
        }
        __syncthreads();
        #pragma unroll
        for (int kk = 0; kk < GBK; kk += 32) {
            bf16x8 af[FM], bfr[FN];
            #pragma unroll
            for (int m = 0; m < FM; ++m) {
                int R = wm*(BM/2) + m*16 + (lane & 15);
                af[m]  = *(const bf16x8*)((const char*)As + R*128 + ((kk*2 + bcol) ^ xr));
            }
            #pragma unroll
            for (int n = 0; n < FN; ++n) {
                int R = wn*(BN/2) + n*16 + (lane & 15);
                bfr[n] = *(const bf16x8*)((const char*)Bs + R*128 + ((kk*2 + bcol) ^ xr));
            }
            #pragma unroll
            for (int m = 0; m < FM; ++m)
                #pragma unroll
                for (int n = 0; n < FN; ++n)
                    acc[m][n] = __builtin_amdgcn_mfma_f32_16x16x32_bf16(af[m], bfr[n], acc[m][n], 0, 0, 0);
        }
        __syncthreads();
    }

    // epilogue: C/D layout col=lane&15, row=(lane>>4)*4+reg
    int cl = lane & 15, rq = lane >> 4;
    #pragma unroll
    for (int m = 0; m < FM; ++m) {
        #pragma unroll
        for (int n = 0; n < FN; ++n) {
            int col = col_base + wn*(BN/2) + n*16 + cl;
            float bv = bias[col];
            float gv = (EPI == 1) ? gvec[col] : 0.f;
            #pragma unroll
            for (int j = 0; j < 4; ++j) {
                int row = row_base + wm*(BM/2) + m*16 + rq*4 + j;
                float v = acc[m][n][j] + bv;
                size_t idx = (size_t)row * N + col;
                if constexpr (EPI == 0) {
                    out[idx] = (OutT)f2bf(v);
                } else if constexpr (EPI == 1) {
                    out[idx] = resid[idx] + gv * v;
                } else { // gelu (tanh approx)
                    float u = 0.7978845608028654f * (v + 0.044715f * v * v * v);
                    out[idx] = (OutT)f2bf(0.5f * v * (1.f + tanhf(u)));
                }
            }
        }
    }
}

// ---------------------------------------------------------------------------
// Kernel 4: NATTEN 7x7 clamped-window attention (bf16 qkv -> bf16 out)
// One wave per (token, head). qkv layout: [tok][q(384) k(384) v(384)]
// ---------------------------------------------------------------------------
__global__ __launch_bounds__(256) void natten_k(const bf16* __restrict__ qkv,
                                                bf16* __restrict__ o)
{
    __shared__ float qs[4][DH];
    __shared__ float ps[4][64];
    int tid  = threadIdx.x;
    int w    = tid >> 6;
    int lane = tid & 63;
    int gw   = blockIdx.x * 4 + w;
    int head = gw % NHD;
    int token = gw / NHD;
    int hrow = token >> 6, wcol = token & 63;
    int sh = min(max(hrow - 3, 0), GH - KW);
    int sw = min(max(wcol - 3, 0), GW - KW);

    qs[w][lane] = __bfloat162float(qkv[(size_t)token * (3*CC) + head * DH + lane]) * 0.125f;
    __syncthreads();

    float score = -INFINITY;
    if (lane < KW*KW) {
        int jr = lane / KW, jc = lane % KW;
        int ntok = (sh + jr) * GW + (sw + jc);
        const uint4* kp = (const uint4*)(qkv + (size_t)ntok * (3*CC) + CC + head * DH);
        const float* qp = qs[w];
        float acc = 0.f;
        #pragma unroll
        for (int i = 0; i < 8; ++i) {
            uint4 kv = kp[i];
            acc += qp[i*8+0] * bf2f(kv.x & 0xffffu) + qp[i*8+1] * bf2f(kv.x >> 16)
                 + qp[i*8+2] * bf2f(kv.y & 0xffffu) + qp[i*8+3] * bf2f(kv.y >> 16)
                 + qp[i*8+4] * bf2f(kv.z & 0xffffu) + qp[i*8+5] * bf2f(kv.z >> 16)
                 + qp[i*8+6] * bf2f(kv.w & 0xffffu) + qp[i*8+7] * bf2f(kv.w >> 16);
        }
        score = acc;
    }
    float mx = score;
    #pragma unroll
    for (int off = 32; off; off >>= 1) mx = fmaxf(mx, __shfl_xor(mx, off));
    float p = (lane < KW*KW) ? expf(score - mx) : 0.f;
    float sm = p;
    #pragma unroll
    for (int off = 32; off; off >>= 1) sm += __shfl_xor(sm, off);
    p /= sm;
    ps[w][lane] = p;
    __syncthreads();

    float od = 0.f;
    #pragma unroll 7
    for (int j = 0; j < KW*KW; ++j) {
        int jr = j / KW, jc = j % KW;
        int ntok = (sh + jr) * GW + (sw + jc);
        od += ps[w][j] * __bfloat162float(qkv[(size_t)ntok * (3*CC) + 2*CC + head * DH + lane]);
    }
    o[(size_t)token * CC + head * DH + lane] = f2bf(od);
}

// ---------------------------------------------------------------------------
// launch
// ---------------------------------------------------------------------------
extern "C" void kernel_launch(void* const* d_in, const int* in_sizes, int n_in,
                              void* d_out, int out_size, void* d_ws, size_t ws_size,
                              hipStream_t stream)
{
    const float* x      = (const float*)d_in[0];
    const float* cond   = (const float*)d_in[1];
    const float* qkv_w  = (const float*)d_in[2];
    const float* qkv_b  = (const float*)d_in[3];
    const float* proj_w = (const float*)d_in[4];
    const float* proj_b = (const float*)d_in[5];
    const float* fc1_w  = (const float*)d_in[6];
    const float* fc1_b  = (const float*)d_in[7];
    const float* fc2_w  = (const float*)d_in[8];
    const float* fc2_b  = (const float*)d_in[9];
    const float* ada_w  = (const float*)d_in[10];
    const float* ada_b  = (const float*)d_in[11];
    float* out = (float*)d_out;

    // scratch layout (bytes)
    char* p = (char*)d_ws;
    float* m       = (float*)p;            p += 6*CC*sizeof(float);
    bf16* y        = (bf16*)p;             p += (size_t)NTOK*CC*2;
    bf16* qkv      = (bf16*)p;             p += (size_t)NTOK*(3*CC)*2;
    bf16* attn_o   = (bf16*)p;             p += (size_t)NTOK*CC*2;
    bf16* hdn      = (bf16*)p;             p += (size_t)NTOK*(4*CC)*2;
    bf16* qkv_wt   = (bf16*)p;             p += (size_t)(3*CC)*CC*2;
    bf16* proj_wt  = (bf16*)p;             p += (size_t)CC*CC*2;
    bf16* fc1_wt   = (bf16*)p;             p += (size_t)(4*CC)*CC*2;
    bf16* fc2_wt   = (bf16*)p;             p += (size_t)CC*(4*CC)*2;

    const float* sh_a = m;
    const float* sc_a = m + CC;
    const float* g_a  = m + 2*CC;
    const float* sh_m = m + 3*CC;
    const float* sc_m = m + 4*CC;
    const float* g_m  = m + 5*CC;

    // 0. weight transposes + ada modulation, one dispatch (1728 + 36 blocks)
    wt_ada_k<<<1764, 256, 0, stream>>>(qkv_w, proj_w, fc1_w, fc2_w,
                                       qkv_wt, proj_wt, fc1_wt, fc2_wt,
                                       cond, ada_w, ada_b, m);
    // 1. y = LN(x)*(1+sc_a)+sh_a
    ln_mod_k<<<NTOK, 128, 0, stream>>>(x, sh_a, sc_a, y);
    // 2. qkv = y @ qkv_w + qkv_b   (bf16 out)  grid (9,32)=288
    mgemm_k<0, bf16, 128, 128><<<dim3((3*CC)/128, NTOK/128), 256, 0, stream>>>(
        y, qkv_wt, qkv_b, nullptr, nullptr, qkv, NTOK, 3*CC, CC);
    // 3. neighborhood attention
    natten_k<<<(NTOK*NHD)/4, 256, 0, stream>>>(qkv, attn_o);
    // 4. x1 = x + g_a * (attn_o @ proj_w + proj_b) -> d_out (f32)  grid (6,64)=384
    mgemm_k<1, float, 64, 64><<<dim3(CC/64, NTOK/64), 256, 0, stream>>>(
        attn_o, proj_wt, proj_b, x, g_a, out, NTOK, CC, CC);
    // 5. y = LN(x1)*(1+sc_m)+sh_m
    ln_mod_k<<<NTOK, 128, 0, stream>>>(out, sh_m, sc_m, y);
    // 6. hdn = gelu(y @ fc1_w + fc1_b)  (bf16 out)  grid (12,32)=384
    mgemm_k<2, bf16, 128, 128><<<dim3((4*CC)/128, NTOK/128), 256, 0, stream>>>(
        y, fc1_wt, fc1_b, nullptr, nullptr, hdn, NTOK, 4*CC, CC);
    // 7. out = x1 + g_m * (hdn @ fc2_w + fc2_b)  (in-place, f32)  grid (6,64)=384
    mgemm_k<1, float, 64, 64><<<dim3(CC/64, NTOK/64), 256, 0, stream>>>(
        hdn, fc2_wt, fc2_b, out, g_m, out, NTOK, CC, 4*CC);
}

// Round 6
// 107.951 us; speedup vs baseline: 1.7798x; 1.0328x over previous
//
#include <hip/hip_runtime.h>
#include <hip/hip_bf16.h>
#include <math.h>

// Problem constants
#define GH 64
#define GW 64
#define CC 384
#define NHD 6
#define KW 7
#define DH 64
#define NTOK (GH*GW)          // 4096
#define LN_EPS 1e-6f

typedef __attribute__((ext_vector_type(4))) float f32x4;
typedef __attribute__((ext_vector_type(8))) short bf16x8;
typedef __hip_bfloat16 bf16;

typedef const __attribute__((address_space(1))) unsigned int* gptr_t;
typedef __attribute__((address_space(3))) unsigned int* lptr_t;

__device__ __forceinline__ float bf2f(unsigned int u16) {
    union { unsigned int i; float f; } c; c.i = u16 << 16; return c.f;
}
__device__ __forceinline__ bf16 f2bf(float f) { return __float2bfloat16(f); }

// ---------------------------------------------------------------------------
// Kernel 1: fused {4 weight transposes} + {ada modulation} in ONE dispatch.
// ---------------------------------------------------------------------------
__global__ __launch_bounds__(256) void wt_ada_k(const float* __restrict__ qkv_w,
                                                const float* __restrict__ proj_w,
                                                const float* __restrict__ fc1_w,
                                                const float* __restrict__ fc2_w,
                                                bf16* __restrict__ qkv_wt,
                                                bf16* __restrict__ proj_wt,
                                                bf16* __restrict__ fc1_wt,
                                                bf16* __restrict__ fc2_wt,
                                                const float* __restrict__ cond,
                                                const float* __restrict__ aw,
                                                const float* __restrict__ ab,
                                                float* __restrict__ m)
{
    int b = blockIdx.x;
    int tid = threadIdx.x;
    if (b >= 1728) {
        __shared__ float s[CC];
        __shared__ float red[4][64];
        for (int i = tid; i < CC; i += 256) {
            float c = cond[i];
            s[i] = c / (1.f + expf(-c));
        }
        __syncthreads();
        int c  = tid & 63;
        int ks = tid >> 6;
        int col = (b - 1728) * 64 + c;
        float acc = 0.f;
        for (int k = ks * 96; k < (ks + 1) * 96; ++k)
            acc += s[k] * aw[(size_t)k * (6*CC) + col];
        red[ks][c] = acc;
        __syncthreads();
        if (tid < 64)
            m[col] = red[0][c] + red[1][c] + red[2][c] + red[3][c] + ab[col];
        return;
    }
    __shared__ float t[32][33];
    const float* in; bf16* outp; int K, N, lid;
    if (b < 432)       { in = qkv_w;  outp = qkv_wt;  K = 384;  N = 1152; lid = b; }
    else if (b < 576)  { in = proj_w; outp = proj_wt; K = 384;  N = 384;  lid = b - 432; }
    else if (b < 1152) { in = fc1_w;  outp = fc1_wt;  K = 384;  N = 1536; lid = b - 576; }
    else               { in = fc2_w;  outp = fc2_wt;  K = 1536; N = 384;  lid = b - 1152; }
    int nbn = N / 32;
    int bn = (lid % nbn) * 32, bk = (lid / nbn) * 32;
    int x = tid & 31, y = tid >> 5;   // (32,8)
    #pragma unroll
    for (int i = 0; i < 32; i += 8)
        t[y + i][x] = in[(size_t)(bk + y + i) * N + bn + x];
    __syncthreads();
    #pragma unroll
    for (int i = 0; i < 32; i += 8)
        outp[(size_t)(bn + y + i) * K + bk + x] = f2bf(t[x][y + i]);
}

// ---------------------------------------------------------------------------
// Kernel 2: y = LN(x) * (1 + sc) + sh   -> bf16   (one block of 128 per token)
// ---------------------------------------------------------------------------
__global__ __launch_bounds__(128) void ln_mod_k(const float* __restrict__ xin,
                                                const float* __restrict__ sh,
                                                const float* __restrict__ sc,
                                                bf16* __restrict__ yout)
{
    int t = blockIdx.x;
    int tid = threadIdx.x;
    const float* xr = xin + (size_t)t * CC;
    float v0 = xr[tid], v1 = xr[tid + 128], v2 = xr[tid + 256];
    float s  = v0 + v1 + v2;
    float ss = v0*v0 + v1*v1 + v2*v2;
    #pragma unroll
    for (int off = 32; off; off >>= 1) {
        s  += __shfl_down(s,  off);
        ss += __shfl_down(ss, off);
    }
    __shared__ float red[4];
    int wid = tid >> 6;
    if ((tid & 63) == 0) { red[wid*2] = s; red[wid*2+1] = ss; }
    __syncthreads();
    s  = red[0] + red[2];
    ss = red[1] + red[3];
    float mean = s * (1.f / CC);
    float var  = ss * (1.f / CC) - mean * mean;
    float rstd = rsqrtf(var + LN_EPS);
    bf16* yr = yout + (size_t)t * CC;
    yr[tid      ] = f2bf((v0 - mean) * rstd * (1.f + sc[tid      ]) + sh[tid      ]);
    yr[tid + 128] = f2bf((v1 - mean) * rstd * (1.f + sc[tid + 128]) + sh[tid + 128]);
    yr[tid + 256] = f2bf((v2 - mean) * rstd * (1.f + sc[tid + 256]) + sh[tid + 256]);
}

// ---------------------------------------------------------------------------
// Kernel 3: MFMA bf16 GEMM, gload_lds(16B) staging + XOR swizzle +
// DOUBLE-BUFFERED with counted vmcnt (loads stay in flight across barriers).
// out[M,N] = A[M,K] @ Bt[N,K]^T + epilogue.  BK=64, 4 waves (2x2).
// EPI: 0 = +bias (bf16) ; 1 = resid + g*(+bias) (f32) ; 2 = gelu(+bias) (bf16)
// ---------------------------------------------------------------------------
#define GBK 64

template<int EPI, typename OutT, int BM, int BN>
__global__ __launch_bounds__(256) void mgemm_k(const bf16* __restrict__ A,   // [M][K]
                                               const bf16* __restrict__ Bt,  // [N][K]
                                               const float* __restrict__ bias,
                                               const float* __restrict__ resid,
                                               const float* __restrict__ gvec,
                                               OutT* __restrict__ out,
                                               int M, int N, int Kd)
{
    constexpr int FM = BM / 32, FN = BN / 32;
    constexpr int LDST = BM/32 + BN/32;     // gload_lds per wave per tile
    __shared__ __align__(16) bf16 As[2][BM][GBK];
    __shared__ __align__(16) bf16 Bs[2][BN][GBK];
    int tid = threadIdx.x;
    int wid = tid >> 6, lane = tid & 63;
    int wm = wid >> 1, wn = wid & 1;

    // XCD-aware bijective block swizzle (all grids used are divisible by 8)
    int gx = gridDim.x;
    int nwg = gx * gridDim.y;
    int bid = blockIdx.y * gx + blockIdx.x;
    int swz = (bid & 7) * (nwg >> 3) + (bid >> 3);
    int bx = swz % gx, by = swz / gx;

    int row_base = by * BM;
    int col_base = bx * BN;

    int l8 = lane >> 3;
    int cs = ((lane & 7) ^ l8) * 8;     // pre-swizzled global k-chunk (elements)
    int xr = (lane & 7) << 4;           // read-side XOR (bytes)
    int bcol = (lane >> 4) * 16;        // read-side k-byte base

    f32x4 acc[FM][FN] = {};
    const int nt = Kd / GBK;

    auto STAGE = [&](int buf, int t) {
        int k0 = t * GBK;
        #pragma unroll
        for (int p = 0; p < BM / 32; ++p) {
            int rb = p * 32 + wid * 8;
            __builtin_amdgcn_global_load_lds(
                (gptr_t)(const void*)(A + (size_t)(row_base + rb + l8) * Kd + k0 + cs),
                (lptr_t)(void*)&As[buf][rb][0], 16, 0, 0);
        }
        #pragma unroll
        for (int p = 0; p < BN / 32; ++p) {
            int rb = p * 32 + wid * 8;
            __builtin_amdgcn_global_load_lds(
                (gptr_t)(const void*)(Bt + (size_t)(col_base + rb + l8) * Kd + k0 + cs),
                (lptr_t)(void*)&Bs[buf][rb][0], 16, 0, 0);
        }
    };

    STAGE(0, 0);
    for (int t = 0; t < nt; ++t) {
        int cur = t & 1;
        if (t + 1 < nt) {
            STAGE(cur ^ 1, t + 1);
            asm volatile("s_waitcnt vmcnt(%0)" :: "n"(LDST) : "memory");
        } else {
            asm volatile("s_waitcnt vmcnt(0)" ::: "memory");
        }
        __builtin_amdgcn_sched_barrier(0);
        __builtin_amdgcn_s_barrier();
        __builtin_amdgcn_sched_barrier(0);
        #pragma unroll
        for (int kk = 0; kk < GBK; kk += 32) {
            bf16x8 af[FM], bfr[FN];
            #pragma unroll
            for (int m = 0; m < FM; ++m) {
                int R = wm*(BM/2) + m*16 + (lane & 15);
                af[m]  = *(const bf16x8*)((const char*)As[cur] + R*128 + ((kk*2 + bcol) ^ xr));
            }
            #pragma unroll
            for (int n = 0; n < FN; ++n) {
                int R = wn*(BN/2) + n*16 + (lane & 15);
                bfr[n] = *(const bf16x8*)((const char*)Bs[cur] + R*128 + ((kk*2 + bcol) ^ xr));
            }
            #pragma unroll
            for (int m = 0; m < FM; ++m)
                #pragma unroll
                for (int n = 0; n < FN; ++n)
                    acc[m][n] = __builtin_amdgcn_mfma_f32_16x16x32_bf16(af[m], bfr[n], acc[m][n], 0, 0, 0);
        }
        __builtin_amdgcn_sched_barrier(0);
        __builtin_amdgcn_s_barrier();
        __builtin_amdgcn_sched_barrier(0);
    }

    // epilogue: C/D layout col=lane&15, row=(lane>>4)*4+reg
    int cl = lane & 15, rq = lane >> 4;
    #pragma unroll
    for (int m = 0; m < FM; ++m) {
        #pragma unroll
        for (int n = 0; n < FN; ++n) {
            int col = col_base + wn*(BN/2) + n*16 + cl;
            float bv = bias[col];
            float gv = (EPI == 1) ? gvec[col] : 0.f;
            #pragma unroll
            for (int j = 0; j < 4; ++j) {
                int row = row_base + wm*(BM/2) + m*16 + rq*4 + j;
                float v = acc[m][n][j] + bv;
                size_t idx = (size_t)row * N + col;
                if constexpr (EPI == 0) {
                    out[idx] = (OutT)f2bf(v);
                } else if constexpr (EPI == 1) {
                    out[idx] = resid[idx] + gv * v;
                } else { // gelu (tanh approx)
                    float u = 0.7978845608028654f * (v + 0.044715f * v * v * v);
                    out[idx] = (OutT)f2bf(0.5f * v * (1.f + tanhf(u)));
                }
            }
        }
    }
}

// ---------------------------------------------------------------------------
// Kernel 4: NATTEN 7x7 clamped-window attention (bf16 qkv -> bf16 out)
// One wave per (token, head). qkv layout: [tok][q(384) k(384) v(384)]
// ---------------------------------------------------------------------------
__global__ __launch_bounds__(256) void natten_k(const bf16* __restrict__ qkv,
                                                bf16* __restrict__ o)
{
    __shared__ float qs[4][DH];
    __shared__ float ps[4][64];
    int tid  = threadIdx.x;
    int w    = tid >> 6;
    int lane = tid & 63;
    int gw   = blockIdx.x * 4 + w;
    int head = gw % NHD;
    int token = gw / NHD;
    int hrow = token >> 6, wcol = token & 63;
    int sh = min(max(hrow - 3, 0), GH - KW);
    int sw = min(max(wcol - 3, 0), GW - KW);

    qs[w][lane] = __bfloat162float(qkv[(size_t)token * (3*CC) + head * DH + lane]) * 0.125f;
    __syncthreads();

    float score = -INFINITY;
    if (lane < KW*KW) {
        int jr = lane / KW, jc = lane % KW;
        int ntok = (sh + jr) * GW + (sw + jc);
        const uint4* kp = (const uint4*)(qkv + (size_t)ntok * (3*CC) + CC + head * DH);
        const float* qp = qs[w];
        float acc = 0.f;
        #pragma unroll
        for (int i = 0; i < 8; ++i) {
            uint4 kv = kp[i];
            acc += qp[i*8+0] * bf2f(kv.x & 0xffffu) + qp[i*8+1] * bf2f(kv.x >> 16)
                 + qp[i*8+2] * bf2f(kv.y & 0xffffu) + qp[i*8+3] * bf2f(kv.y >> 16)
                 + qp[i*8+4] * bf2f(kv.z & 0xffffu) + qp[i*8+5] * bf2f(kv.z >> 16)
                 + qp[i*8+6] * bf2f(kv.w & 0xffffu) + qp[i*8+7] * bf2f(kv.w >> 16);
        }
        score = acc;
    }
    float mx = score;
    #pragma unroll
    for (int off = 32; off; off >>= 1) mx = fmaxf(mx, __shfl_xor(mx, off));
    float p = (lane < KW*KW) ? expf(score - mx) : 0.f;
    float sm = p;
    #pragma unroll
    for (int off = 32; off; off >>= 1) sm += __shfl_xor(sm, off);
    p /= sm;
    ps[w][lane] = p;
    __syncthreads();

    float od = 0.f;
    #pragma unroll
    for (int j = 0; j < KW*KW; ++j) {          // full unroll: jr/jc fold to consts
        int jr = j / KW, jc = j % KW;
        int ntok = (sh + jr) * GW + (sw + jc);
        od += ps[w][j] * __bfloat162float(qkv[(size_t)ntok * (3*CC) + 2*CC + head * DH + lane]);
    }
    o[(size_t)token * CC + head * DH + lane] = f2bf(od);
}

// ---------------------------------------------------------------------------
// launch
// ---------------------------------------------------------------------------
extern "C" void kernel_launch(void* const* d_in, const int* in_sizes, int n_in,
                              void* d_out, int out_size, void* d_ws, size_t ws_size,
                              hipStream_t stream)
{
    const float* x      = (const float*)d_in[0];
    const float* cond   = (const float*)d_in[1];
    const float* qkv_w  = (const float*)d_in[2];
    const float* qkv_b  = (const float*)d_in[3];
    const float* proj_w = (const float*)d_in[4];
    const float* proj_b = (const float*)d_in[5];
    const float* fc1_w  = (const float*)d_in[6];
    const float* fc1_b  = (const float*)d_in[7];
    const float* fc2_w  = (const float*)d_in[8];
    const float* fc2_b  = (const float*)d_in[9];
    const float* ada_w  = (const float*)d_in[10];
    const float* ada_b  = (const float*)d_in[11];
    float* out = (float*)d_out;

    // scratch layout (bytes)
    char* p = (char*)d_ws;
    float* m       = (float*)p;            p += 6*CC*sizeof(float);
    bf16* y        = (bf16*)p;             p += (size_t)NTOK*CC*2;
    bf16* qkv      = (bf16*)p;             p += (size_t)NTOK*(3*CC)*2;
    bf16* attn_o   = (bf16*)p;             p += (size_t)NTOK*CC*2;
    bf16* hdn      = (bf16*)p;             p += (size_t)NTOK*(4*CC)*2;
    bf16* qkv_wt   = (bf16*)p;             p += (size_t)(3*CC)*CC*2;
    bf16* proj_wt  = (bf16*)p;             p += (size_t)CC*CC*2;
    bf16* fc1_wt   = (bf16*)p;             p += (size_t)(4*CC)*CC*2;
    bf16* fc2_wt   = (bf16*)p;             p += (size_t)CC*(4*CC)*2;

    const float* sh_a = m;
    const float* sc_a = m + CC;
    const float* g_a  = m + 2*CC;
    const float* sh_m = m + 3*CC;
    const float* sc_m = m + 4*CC;
    const float* g_m  = m + 5*CC;

    // 0. weight transposes + ada modulation, one dispatch (1728 + 36 blocks)
    wt_ada_k<<<1764, 256, 0, stream>>>(qkv_w, proj_w, fc1_w, fc2_w,
                                       qkv_wt, proj_wt, fc1_wt, fc2_wt,
                                       cond, ada_w, ada_b, m);
    // 1. y = LN(x)*(1+sc_a)+sh_a
    ln_mod_k<<<NTOK, 128, 0, stream>>>(x, sh_a, sc_a, y);
    // 2. qkv = y @ qkv_w + qkv_b   (bf16 out)  grid (9,32)=288
    mgemm_k<0, bf16, 128, 128><<<dim3((3*CC)/128, NTOK/128), 256, 0, stream>>>(
        y, qkv_wt, qkv_b, nullptr, nullptr, qkv, NTOK, 3*CC, CC);
    // 3. neighborhood attention
    natten_k<<<(NTOK*NHD)/4, 256, 0, stream>>>(qkv, attn_o);
    // 4. x1 = x + g_a * (attn_o @ proj_w + proj_b) -> d_out (f32)  grid (6,64)=384
    mgemm_k<1, float, 64, 64><<<dim3(CC/64, NTOK/64), 256, 0, stream>>>(
        attn_o, proj_wt, proj_b, x, g_a, out, NTOK, CC, CC);
    // 5. y = LN(x1)*(1+sc_m)+sh_m
    ln_mod_k<<<NTOK, 128, 0, stream>>>(out, sh_m, sc_m, y);
    // 6. hdn = gelu(y @ fc1_w + fc1_b)  (bf16 out)  grid (12,32)=384
    mgemm_k<2, bf16, 128, 128><<<dim3((4*CC)/128, NTOK/128), 256, 0, stream>>>(
        y, fc1_wt, fc1_b, nullptr, nullptr, hdn, NTOK, 4*CC, CC);
    // 7. out = x1 + g_m * (hdn @ fc2_w + fc2_b)  (in-place, f32)  grid (6,64)=384
    mgemm_k<1, float, 64, 64><<<dim3(CC/64, NTOK/64), 256, 0, stream>>>(
        hdn, fc2_wt, fc2_b, out, g_m, out, NTOK, CC, 4*CC);
}

// Round 8
// 105.857 us; speedup vs baseline: 1.8150x; 1.0198x over previous
//
#include <hip/hip_runtime.h>
#include <hip/hip_bf16.h>
#include <math.h>

// Problem constants
#define GH 64
#define GW 64
#define CC 384
#define NHD 6
#define KW 7
#define DH 64
#define NTOK (GH*GW)          // 4096
#define LN_EPS 1e-6f

typedef __attribute__((ext_vector_type(4))) float f32x4;
typedef __attribute__((ext_vector_type(8))) short bf16x8;
typedef __hip_bfloat16 bf16;

typedef const __attribute__((address_space(1))) unsigned int* gptr_t;
typedef __attribute__((address_space(3))) unsigned int* lptr_t;

__device__ __forceinline__ float bf2f(unsigned int u16) {
    union { unsigned int i; float f; } c; c.i = u16 << 16; return c.f;
}
__device__ __forceinline__ bf16 f2bf(float f) { return __float2bfloat16(f); }

// ---------------------------------------------------------------------------
// Kernel 1: fused {4 weight transposes (64x64 tiles, vectorized)} + {ada}.
// tiles: qkv 18*6=108 | proj 6*6=36 | fc1 24*6=144 | fc2 6*24=144  => 432
// blocks 432..467: m = silu(cond) @ ada_w + ada_b (64 cols each)
// ---------------------------------------------------------------------------
__global__ __launch_bounds__(256) void wt_ada_k(const float* __restrict__ qkv_w,
                                                const float* __restrict__ proj_w,
                                                const float* __restrict__ fc1_w,
                                                const float* __restrict__ fc2_w,
                                                bf16* __restrict__ qkv_wt,
                                                bf16* __restrict__ proj_wt,
                                                bf16* __restrict__ fc1_wt,
                                                bf16* __restrict__ fc2_wt,
                                                const float* __restrict__ cond,
                                                const float* __restrict__ aw,
                                                const float* __restrict__ ab,
                                                float* __restrict__ m)
{
    int b = blockIdx.x;
    int tid = threadIdx.x;
    if (b >= 432) {
        __shared__ float s[CC];
        __shared__ float red[4][64];
        for (int i = tid; i < CC; i += 256) {
            float c = cond[i];
            s[i] = c / (1.f + expf(-c));
        }
        __syncthreads();
        int c  = tid & 63;
        int ks = tid >> 6;
        int col = (b - 432) * 64 + c;
        float acc = 0.f;
        for (int k = ks * 96; k < (ks + 1) * 96; ++k)
            acc += s[k] * aw[(size_t)k * (6*CC) + col];
        red[ks][c] = acc;
        __syncthreads();
        if (tid < 64)
            m[col] = red[0][c] + red[1][c] + red[2][c] + red[3][c] + ab[col];
        return;
    }
    // ---- 64x64 transpose tile, vectorized both sides ----
    __shared__ float t[64][65];
    const float* in; bf16* outp; int K, N, lid;
    if (b < 108)       { in = qkv_w;  outp = qkv_wt;  K = 384;  N = 1152; lid = b; }
    else if (b < 144)  { in = proj_w; outp = proj_wt; K = 384;  N = 384;  lid = b - 108; }
    else if (b < 288)  { in = fc1_w;  outp = fc1_wt;  K = 384;  N = 1536; lid = b - 144; }
    else               { in = fc2_w;  outp = fc2_wt;  K = 1536; N = 384;  lid = b - 288; }
    int nbn = N >> 6;
    int bn = (lid % nbn) << 6, bk = (lid / nbn) << 6;
    int c4 = (tid & 15) * 4, r0 = tid >> 4;       // 16 rows/pass
    #pragma unroll
    for (int p = 0; p < 4; ++p) {
        int r = r0 + p * 16;
        float4 v = *(const float4*)&in[(size_t)(bk + r) * N + bn + c4];
        t[r][c4+0] = v.x; t[r][c4+1] = v.y; t[r][c4+2] = v.z; t[r][c4+3] = v.w;
    }
    __syncthreads();
    #pragma unroll
    for (int p = 0; p < 4; ++p) {
        int n = r0 + p * 16;                       // local col -> out row
        ushort4 w;
        w.x = __bfloat16_as_ushort(f2bf(t[c4+0][n]));
        w.y = __bfloat16_as_ushort(f2bf(t[c4+1][n]));
        w.z = __bfloat16_as_ushort(f2bf(t[c4+2][n]));
        w.w = __bfloat16_as_ushort(f2bf(t[c4+3][n]));
        *(ushort4*)&outp[(size_t)(bn + n) * K + bk + c4] = w;
    }
}

// ---------------------------------------------------------------------------
// Kernel 2: y = LN(x) * (1 + sc) + sh   -> bf16   (one block of 128 per token)
// ---------------------------------------------------------------------------
__global__ __launch_bounds__(128) void ln_mod_k(const float* __restrict__ xin,
                                                const float* __restrict__ sh,
                                                const float* __restrict__ sc,
                                                bf16* __restrict__ yout)
{
    int t = blockIdx.x;
    int tid = threadIdx.x;
    const float* xr = xin + (size_t)t * CC;
    float v0 = xr[tid], v1 = xr[tid + 128], v2 = xr[tid + 256];
    float s  = v0 + v1 + v2;
    float ss = v0*v0 + v1*v1 + v2*v2;
    #pragma unroll
    for (int off = 32; off; off >>= 1) {
        s  += __shfl_down(s,  off);
        ss += __shfl_down(ss, off);
    }
    __shared__ float red[4];
    int wid = tid >> 6;
    if ((tid & 63) == 0) { red[wid*2] = s; red[wid*2+1] = ss; }
    __syncthreads();
    s  = red[0] + red[2];
    ss = red[1] + red[3];
    float mean = s * (1.f / CC);
    float var  = ss * (1.f / CC) - mean * mean;
    float rstd = rsqrtf(var + LN_EPS);
    bf16* yr = yout + (size_t)t * CC;
    yr[tid      ] = f2bf((v0 - mean) * rstd * (1.f + sc[tid      ]) + sh[tid      ]);
    yr[tid + 128] = f2bf((v1 - mean) * rstd * (1.f + sc[tid + 128]) + sh[tid + 128]);
    yr[tid + 256] = f2bf((v2 - mean) * rstd * (1.f + sc[tid + 256]) + sh[tid + 256]);
}

// ---------------------------------------------------------------------------
// Kernel 3: MFMA bf16 GEMM, gload_lds(16B) + XOR swizzle + DEPTH-stage
// pipeline with counted vmcnt.  TPB=256 (4 waves 2x2) or 512 (8 waves 2x4).
// EPI: 0 = +bias (bf16) ; 1 = resid + g*(+bias) (f32) ; 2 = gelu(+bias) (bf16)
// ---------------------------------------------------------------------------
#define GBK 64

template<int EPI, typename OutT, int BM, int BN, int TPB, int DEPTH>
__global__ __launch_bounds__(TPB) void mgemm_k(const bf16* __restrict__ A,   // [M][K]
                                               const bf16* __restrict__ Bt,  // [N][K]
                                               const float* __restrict__ bias,
                                               const float* __restrict__ resid,
                                               const float* __restrict__ gvec,
                                               OutT* __restrict__ out,
                                               int M, int N, int Kd)
{
    constexpr int WR = 2, WC = TPB / 128;            // wave grid (rows x cols)
    constexpr int FM = BM / WR / 16, FN = BN / WC / 16;
    constexpr int RPP = TPB / 8;                     // rows staged per pass
    constexpr int PA = BM / RPP, PB = BN / RPP;      // passes per operand
    constexpr int LDST = PA + PB;                    // gloads per wave per tile
    __shared__ __align__(16) bf16 As[DEPTH][BM][GBK];
    __shared__ __align__(16) bf16 Bs[DEPTH][BN][GBK];
    int tid = threadIdx.x;
    int wid = tid >> 6, lane = tid & 63;
    int wm = wid / WC, wn = wid % WC;

    // XCD-aware bijective block swizzle (all grids used are divisible by 8)
    int gx = gridDim.x;
    int nwg = gx * gridDim.y;
    int bid = blockIdx.y * gx + blockIdx.x;
    int swz = (bid & 7) * (nwg >> 3) + (bid >> 3);
    int bx = swz % gx, by = swz / gx;

    int row_base = by * BM;
    int col_base = bx * BN;

    int l8 = lane >> 3;
    int cs = ((lane & 7) ^ l8) * 8;     // pre-swizzled global k-chunk (elements)
    int xr = (lane & 7) << 4;           // read-side XOR (bytes)
    int bcol = (lane >> 4) * 16;        // read-side k-byte base

    f32x4 acc[FM][FN] = {};
    const int nt = Kd / GBK;

    auto STAGE = [&](int buf, int t) {
        int k0 = t * GBK;
        #pragma unroll
        for (int p = 0; p < PA; ++p) {
            int rb = p * RPP + wid * 8;
            __builtin_amdgcn_global_load_lds(
                (gptr_t)(const void*)(A + (size_t)(row_base + rb + l8) * Kd + k0 + cs),
                (lptr_t)(void*)&As[buf][rb][0], 16, 0, 0);
        }
        #pragma unroll
        for (int p = 0; p < PB; ++p) {
            int rb = p * RPP + wid * 8;
            __builtin_amdgcn_global_load_lds(
                (gptr_t)(const void*)(Bt + (size_t)(col_base + rb + l8) * Kd + k0 + cs),
                (lptr_t)(void*)&Bs[buf][rb][0], 16, 0, 0);
        }
    };

    #pragma unroll
    for (int d = 0; d < DEPTH - 1; ++d) STAGE(d, d);

    int cur = 0;
    for (int t = 0; t < nt; ++t) {
        if (t + DEPTH - 1 < nt)
            STAGE((cur + DEPTH - 1) % DEPTH, t + DEPTH - 1);
        int ahead = min(nt - 1, t + DEPTH - 1) - t;
        if constexpr (DEPTH == 3) {
            if (ahead == 2)      asm volatile("s_waitcnt vmcnt(%0)" :: "n"(2*LDST) : "memory");
            else if (ahead == 1) asm volatile("s_waitcnt vmcnt(%0)" :: "n"(LDST)   : "memory");
            else                 asm volatile("s_waitcnt vmcnt(0)" ::: "memory");
        } else {
            if (ahead == 1)      asm volatile("s_waitcnt vmcnt(%0)" :: "n"(LDST)   : "memory");
            else                 asm volatile("s_waitcnt vmcnt(0)" ::: "memory");
        }
        __builtin_amdgcn_sched_barrier(0);
        __builtin_amdgcn_s_barrier();
        __builtin_amdgcn_sched_barrier(0);
        #pragma unroll
        for (int kk = 0; kk < GBK; kk += 32) {
            bf16x8 af[FM], bfr[FN];
            #pragma unroll
            for (int m = 0; m < FM; ++m) {
                int R = wm*(BM/WR) + m*16 + (lane & 15);
                af[m]  = *(const bf16x8*)((const char*)As[cur] + R*128 + ((kk*2 + bcol) ^ xr));
            }
            #pragma unroll
            for (int n = 0; n < FN; ++n) {
                int R = wn*(BN/WC) + n*16 + (lane & 15);
                bfr[n] = *(const bf16x8*)((const char*)Bs[cur] + R*128 + ((kk*2 + bcol) ^ xr));
            }
            #pragma unroll
            for (int m = 0; m < FM; ++m)
                #pragma unroll
                for (int n = 0; n < FN; ++n)
                    acc[m][n] = __builtin_amdgcn_mfma_f32_16x16x32_bf16(af[m], bfr[n], acc[m][n], 0, 0, 0);
        }
        __builtin_amdgcn_sched_barrier(0);
        __builtin_amdgcn_s_barrier();
        __builtin_amdgcn_sched_barrier(0);
        cur = (cur + 1 == DEPTH) ? 0 : cur + 1;
    }

    // epilogue: C/D layout col=lane&15, row=(lane>>4)*4+reg
    int cl = lane & 15, rq = lane >> 4;
    #pragma unroll
    for (int m = 0; m < FM; ++m) {
        #pragma unroll
        for (int n = 0; n < FN; ++n) {
            int col = col_base + wn*(BN/WC) + n*16 + cl;
            float bv = bias[col];
            float gv = (EPI == 1) ? gvec[col] : 0.f;
            #pragma unroll
            for (int j = 0; j < 4; ++j) {
                int row = row_base + wm*(BM/WR) + m*16 + rq*4 + j;
                float v = acc[m][n][j] + bv;
                size_t idx = (size_t)row * N + col;
                if constexpr (EPI == 0) {
                    out[idx] = (OutT)f2bf(v);
                } else if constexpr (EPI == 1) {
                    out[idx] = resid[idx] + gv * v;
                } else { // gelu (tanh approx)
                    float u = 0.7978845608028654f * (v + 0.044715f * v * v * v);
                    out[idx] = (OutT)f2bf(0.5f * v * (1.f + tanhf(u)));
                }
            }
        }
    }
}

// ---------------------------------------------------------------------------
// Kernel 4: NATTEN 7x7 clamped-window attention (bf16 qkv -> bf16 out)
// One wave per (token, head). qkv layout: [tok][q(384) k(384) v(384)]
// ---------------------------------------------------------------------------
__global__ __launch_bounds__(256) void natten_k(const bf16* __restrict__ qkv,
                                                bf16* __restrict__ o)
{
    __shared__ float qs[4][DH];
    __shared__ float ps[4][64];
    int tid  = threadIdx.x;
    int w    = tid >> 6;
    int lane = tid & 63;
    int gw   = blockIdx.x * 4 + w;
    int head = gw % NHD;
    int token = gw / NHD;
    int hrow = token >> 6, wcol = token & 63;
    int sh = min(max(hrow - 3, 0), GH - KW);
    int sw = min(max(wcol - 3, 0), GW - KW);

    qs[w][lane] = __bfloat162float(qkv[(size_t)token * (3*CC) + head * DH + lane]) * 0.125f;
    __syncthreads();

    float score = -INFINITY;
    if (lane < KW*KW) {
        int jr = lane / KW, jc = lane % KW;
        int ntok = (sh + jr) * GW + (sw + jc);
        const uint4* kp = (const uint4*)(qkv + (size_t)ntok * (3*CC) + CC + head * DH);
        const float* qp = qs[w];
        float acc = 0.f;
        #pragma unroll
        for (int i = 0; i < 8; ++i) {
            uint4 kv = kp[i];
            acc += qp[i*8+0] * bf2f(kv.x & 0xffffu) + qp[i*8+1] * bf2f(kv.x >> 16)
                 + qp[i*8+2] * bf2f(kv.y & 0xffffu) + qp[i*8+3] * bf2f(kv.y >> 16)
                 + qp[i*8+4] * bf2f(kv.z & 0xffffu) + qp[i*8+5] * bf2f(kv.z >> 16)
                 + qp[i*8+6] * bf2f(kv.w & 0xffffu) + qp[i*8+7] * bf2f(kv.w >> 16);
        }
        score = acc;
    }
    float mx = score;
    #pragma unroll
    for (int off = 32; off; off >>= 1) mx = fmaxf(mx, __shfl_xor(mx, off));
    float p = (lane < KW*KW) ? expf(score - mx) : 0.f;
    float sm = p;
    #pragma unroll
    for (int off = 32; off; off >>= 1) sm += __shfl_xor(sm, off);
    p /= sm;
    ps[w][lane] = p;
    __syncthreads();

    float od = 0.f;
    #pragma unroll
    for (int j = 0; j < KW*KW; ++j) {          // full unroll: jr/jc fold to consts
        int jr = j / KW, jc = j % KW;
        int ntok = (sh + jr) * GW + (sw + jc);
        od += ps[w][j] * __bfloat162float(qkv[(size_t)ntok * (3*CC) + 2*CC + head * DH + lane]);
    }
    o[(size_t)token * CC + head * DH + lane] = f2bf(od);
}

// ---------------------------------------------------------------------------
// launch
// ---------------------------------------------------------------------------
extern "C" void kernel_launch(void* const* d_in, const int* in_sizes, int n_in,
                              void* d_out, int out_size, void* d_ws, size_t ws_size,
                              hipStream_t stream)
{
    const float* x      = (const float*)d_in[0];
    const float* cond   = (const float*)d_in[1];
    const float* qkv_w  = (const float*)d_in[2];
    const float* qkv_b  = (const float*)d_in[3];
    const float* proj_w = (const float*)d_in[4];
    const float* proj_b = (const float*)d_in[5];
    const float* fc1_w  = (const float*)d_in[6];
    const float* fc1_b  = (const float*)d_in[7];
    const float* fc2_w  = (const float*)d_in[8];
    const float* fc2_b  = (const float*)d_in[9];
    const float* ada_w  = (const float*)d_in[10];
    const float* ada_b  = (const float*)d_in[11];
    float* out = (float*)d_out;

    // scratch layout (bytes)
    char* p = (char*)d_ws;
    float* m       = (float*)p;            p += 6*CC*sizeof(float);
    bf16* y        = (bf16*)p;             p += (size_t)NTOK*CC*2;
    bf16* qkv      = (bf16*)p;             p += (size_t)NTOK*(3*CC)*2;
    bf16* attn_o   = (bf16*)p;             p += (size_t)NTOK*CC*2;
    bf16* hdn      = (bf16*)p;             p += (size_t)NTOK*(4*CC)*2;
    bf16* qkv_wt   = (bf16*)p;             p += (size_t)(3*CC)*CC*2;
    bf16* proj_wt  = (bf16*)p;             p += (size_t)CC*CC*2;
    bf16* fc1_wt   = (bf16*)p;             p += (size_t)(4*CC)*CC*2;
    bf16* fc2_wt   = (bf16*)p;             p += (size_t)CC*(4*CC)*2;

    const float* sh_a = m;
    const float* sc_a = m + CC;
    const float* g_a  = m + 2*CC;
    const float* sh_m = m + 3*CC;
    const float* sc_m = m + 4*CC;
    const float* g_m  = m + 5*CC;

    // 0. weight transposes (64x64, vectorized) + ada modulation (432+36 blocks)
    wt_ada_k<<<468, 256, 0, stream>>>(qkv_w, proj_w, fc1_w, fc2_w,
                                      qkv_wt, proj_wt, fc1_wt, fc2_wt,
                                      cond, ada_w, ada_b, m);
    // 1. y = LN(x)*(1+sc_a)+sh_a
    ln_mod_k<<<NTOK, 128, 0, stream>>>(x, sh_a, sc_a, y);
    // 2. qkv = y @ qkv_w + qkv_b   (bf16 out)  grid (9,32)=288, 8 waves
    mgemm_k<0, bf16, 128, 128, 512, 2><<<dim3((3*CC)/128, NTOK/128), 512, 0, stream>>>(
        y, qkv_wt, qkv_b, nullptr, nullptr, qkv, NTOK, 3*CC, CC);
    // 3. neighborhood attention
    natten_k<<<(NTOK*NHD)/4, 256, 0, stream>>>(qkv, attn_o);
    // 4. x1 = x + g_a * (attn_o @ proj_w + proj_b) -> d_out (f32)  grid (6,64)=384, depth 3
    mgemm_k<1, float, 64, 64, 256, 3><<<dim3(CC/64, NTOK/64), 256, 0, stream>>>(
        attn_o, proj_wt, proj_b, x, g_a, out, NTOK, CC, CC);
    // 5. y = LN(x1)*(1+sc_m)+sh_m
    ln_mod_k<<<NTOK, 128, 0, stream>>>(out, sh_m, sc_m, y);
    // 6. hdn = gelu(y @ fc1_w + fc1_b)  (bf16 out)  grid (12,32)=384, 8 waves
    mgemm_k<2, bf16, 128, 128, 512, 2><<<dim3((4*CC)/128, NTOK/128), 512, 0, stream>>>(
        y, fc1_wt, fc1_b, nullptr, nullptr, hdn, NTOK, 4*CC, CC);
    // 7. out = x1 + g_m * (hdn @ fc2_w + fc2_b)  (in-place, f32)  grid (6,64)=384, depth 3
    mgemm_k<1, float, 64, 64, 256, 3><<<dim3(CC/64, NTOK/64), 256, 0, stream>>>(
        hdn, fc2_wt, fc2_b, out, g_m, out, NTOK, CC, 4*CC);
}

// Round 10
// 86.761 us; speedup vs baseline: 2.2145x; 1.2201x over previous
//
#include <hip/hip_runtime.h>
#include <hip/hip_bf16.h>
#include <math.h>

// Problem constants
#define GH 64
#define GW 64
#define CC 384
#define NHD 6
#define KW 7
#define DH 64
#define NTOK (GH*GW)          // 4096
#define LN_EPS 1e-6f

typedef __attribute__((ext_vector_type(4))) float f32x4;
typedef __attribute__((ext_vector_type(8))) short bf16x8;
typedef __hip_bfloat16 bf16;

typedef const __attribute__((address_space(1))) unsigned int* gptr_t;
typedef __attribute__((address_space(3))) unsigned int* lptr_t;

__device__ __forceinline__ float bf2f(unsigned int u16) {
    union { unsigned int i; float f; } c; c.i = u16 << 16; return c.f;
}
__device__ __forceinline__ bf16 f2bf(float f) { return __float2bfloat16(f); }

// ---------------------------------------------------------------------------
// Kernel 1: fused {4 weight transposes (64x64 tiles, vectorized)} + {ada}.
// ---------------------------------------------------------------------------
__global__ __launch_bounds__(256) void wt_ada_k(const float* __restrict__ qkv_w,
                                                const float* __restrict__ proj_w,
                                                const float* __restrict__ fc1_w,
                                                const float* __restrict__ fc2_w,
                                                bf16* __restrict__ qkv_wt,
                                                bf16* __restrict__ proj_wt,
                                                bf16* __restrict__ fc1_wt,
                                                bf16* __restrict__ fc2_wt,
                                                const float* __restrict__ cond,
                                                const float* __restrict__ aw,
                                                const float* __restrict__ ab,
                                                float* __restrict__ m)
{
    int b = blockIdx.x;
    int tid = threadIdx.x;
    if (b >= 432) {
        __shared__ float s[CC];
        __shared__ float red[4][64];
        for (int i = tid; i < CC; i += 256) {
            float c = cond[i];
            s[i] = c / (1.f + __expf(-c));
        }
        __syncthreads();
        int c  = tid & 63;
        int ks = tid >> 6;
        int col = (b - 432) * 64 + c;
        float acc = 0.f;
        for (int k = ks * 96; k < (ks + 1) * 96; ++k)
            acc += s[k] * aw[(size_t)k * (6*CC) + col];
        red[ks][c] = acc;
        __syncthreads();
        if (tid < 64)
            m[col] = red[0][c] + red[1][c] + red[2][c] + red[3][c] + ab[col];
        return;
    }
    __shared__ float t[64][65];
    const float* in; bf16* outp; int K, N, lid;
    if (b < 108)       { in = qkv_w;  outp = qkv_wt;  K = 384;  N = 1152; lid = b; }
    else if (b < 144)  { in = proj_w; outp = proj_wt; K = 384;  N = 384;  lid = b - 108; }
    else if (b < 288)  { in = fc1_w;  outp = fc1_wt;  K = 384;  N = 1536; lid = b - 144; }
    else               { in = fc2_w;  outp = fc2_wt;  K = 1536; N = 384;  lid = b - 288; }
    int nbn = N >> 6;
    int bn = (lid % nbn) << 6, bk = (lid / nbn) << 6;
    int c4 = (tid & 15) * 4, r0 = tid >> 4;
    #pragma unroll
    for (int p = 0; p < 4; ++p) {
        int r = r0 + p * 16;
        float4 v = *(const float4*)&in[(size_t)(bk + r) * N + bn + c4];
        t[r][c4+0] = v.x; t[r][c4+1] = v.y; t[r][c4+2] = v.z; t[r][c4+3] = v.w;
    }
    __syncthreads();
    #pragma unroll
    for (int p = 0; p < 4; ++p) {
        int n = r0 + p * 16;
        ushort4 w;
        w.x = __bfloat16_as_ushort(f2bf(t[c4+0][n]));
        w.y = __bfloat16_as_ushort(f2bf(t[c4+1][n]));
        w.z = __bfloat16_as_ushort(f2bf(t[c4+2][n]));
        w.w = __bfloat16_as_ushort(f2bf(t[c4+3][n]));
        *(ushort4*)&outp[(size_t)(bn + n) * K + bk + c4] = w;
    }
}

// ---------------------------------------------------------------------------
// Kernel 2: y = LN(x) * (1 + sc) + sh   -> bf16
// ---------------------------------------------------------------------------
__global__ __launch_bounds__(128) void ln_mod_k(const float* __restrict__ xin,
                                                const float* __restrict__ sh,
                                                const float* __restrict__ sc,
                                                bf16* __restrict__ yout)
{
    int t = blockIdx.x;
    int tid = threadIdx.x;
    const float* xr = xin + (size_t)t * CC;
    float v0 = xr[tid], v1 = xr[tid + 128], v2 = xr[tid + 256];
    float s  = v0 + v1 + v2;
    float ss = v0*v0 + v1*v1 + v2*v2;
    #pragma unroll
    for (int off = 32; off; off >>= 1) {
        s  += __shfl_down(s,  off);
        ss += __shfl_down(ss, off);
    }
    __shared__ float red[4];
    int wid = tid >> 6;
    if ((tid & 63) == 0) { red[wid*2] = s; red[wid*2+1] = ss; }
    __syncthreads();
    s  = red[0] + red[2];
    ss = red[1] + red[3];
    float mean = s * (1.f / CC);
    float var  = ss * (1.f / CC) - mean * mean;
    float rstd = rsqrtf(var + LN_EPS);
    bf16* yr = yout + (size_t)t * CC;
    yr[tid      ] = f2bf((v0 - mean) * rstd * (1.f + sc[tid      ]) + sh[tid      ]);
    yr[tid + 128] = f2bf((v1 - mean) * rstd * (1.f + sc[tid + 128]) + sh[tid + 128]);
    yr[tid + 256] = f2bf((v2 - mean) * rstd * (1.f + sc[tid + 256]) + sh[tid + 256]);
}

// ---------------------------------------------------------------------------
// Kernel 3: MFMA bf16 GEMM (structure proven in R6/R8)
// ---------------------------------------------------------------------------
#define GBK 64

template<int EPI, typename OutT, int BM, int BN, int TPB, int DEPTH>
__global__ __launch_bounds__(TPB) void mgemm_k(const bf16* __restrict__ A,
                                               const bf16* __restrict__ Bt,
                                               const float* __restrict__ bias,
                                               const float* __restrict__ resid,
                                               const float* __restrict__ gvec,
                                               OutT* __restrict__ out,
                                               int M, int N, int Kd)
{
    constexpr int WR = 2, WC = TPB / 128;
    constexpr int FM = BM / WR / 16, FN = BN / WC / 16;
    constexpr int RPP = TPB / 8;
    constexpr int PA = BM / RPP, PB = BN / RPP;
    constexpr int LDST = PA + PB;
    __shared__ __align__(16) bf16 As[DEPTH][BM][GBK];
    __shared__ __align__(16) bf16 Bs[DEPTH][BN][GBK];
    int tid = threadIdx.x;
    int wid = tid >> 6, lane = tid & 63;
    int wm = wid / WC, wn = wid % WC;

    int gx = gridDim.x;
    int nwg = gx * gridDim.y;
    int bid = blockIdx.y * gx + blockIdx.x;
    int swz = (bid & 7) * (nwg >> 3) + (bid >> 3);
    int bx = swz % gx, by = swz / gx;

    int row_base = by * BM;
    int col_base = bx * BN;

    int l8 = lane >> 3;
    int cs = ((lane & 7) ^ l8) * 8;
    int xr = (lane & 7) << 4;
    int bcol = (lane >> 4) * 16;

    f32x4 acc[FM][FN] = {};
    const int nt = Kd / GBK;

    auto STAGE = [&](int buf, int t) {
        int k0 = t * GBK;
        #pragma unroll
        for (int p = 0; p < PA; ++p) {
            int rb = p * RPP + wid * 8;
            __builtin_amdgcn_global_load_lds(
                (gptr_t)(const void*)(A + (size_t)(row_base + rb + l8) * Kd + k0 + cs),
                (lptr_t)(void*)&As[buf][rb][0], 16, 0, 0);
        }
        #pragma unroll
        for (int p = 0; p < PB; ++p) {
            int rb = p * RPP + wid * 8;
            __builtin_amdgcn_global_load_lds(
                (gptr_t)(const void*)(Bt + (size_t)(col_base + rb + l8) * Kd + k0 + cs),
                (lptr_t)(void*)&Bs[buf][rb][0], 16, 0, 0);
        }
    };

    #pragma unroll
    for (int d = 0; d < DEPTH - 1; ++d) STAGE(d, d);

    int cur = 0;
    for (int t = 0; t < nt; ++t) {
        if (t + DEPTH - 1 < nt)
            STAGE((cur + DEPTH - 1) % DEPTH, t + DEPTH - 1);
        int ahead = min(nt - 1, t + DEPTH - 1) - t;
        if constexpr (DEPTH == 3) {
            if (ahead == 2)      asm volatile("s_waitcnt vmcnt(%0)" :: "n"(2*LDST) : "memory");
            else if (ahead == 1) asm volatile("s_waitcnt vmcnt(%0)" :: "n"(LDST)   : "memory");
            else                 asm volatile("s_waitcnt vmcnt(0)" ::: "memory");
        } else {
            if (ahead == 1)      asm volatile("s_waitcnt vmcnt(%0)" :: "n"(LDST)   : "memory");
            else                 asm volatile("s_waitcnt vmcnt(0)" ::: "memory");
        }
        __builtin_amdgcn_sched_barrier(0);
        __builtin_amdgcn_s_barrier();
        __builtin_amdgcn_sched_barrier(0);
        #pragma unroll
        for (int kk = 0; kk < GBK; kk += 32) {
            bf16x8 af[FM], bfr[FN];
            #pragma unroll
            for (int m = 0; m < FM; ++m) {
                int R = wm*(BM/WR) + m*16 + (lane & 15);
                af[m]  = *(const bf16x8*)((const char*)As[cur] + R*128 + ((kk*2 + bcol) ^ xr));
            }
            #pragma unroll
            for (int n = 0; n < FN; ++n) {
                int R = wn*(BN/WC) + n*16 + (lane & 15);
                bfr[n] = *(const bf16x8*)((const char*)Bs[cur] + R*128 + ((kk*2 + bcol) ^ xr));
            }
            #pragma unroll
            for (int m = 0; m < FM; ++m)
                #pragma unroll
                for (int n = 0; n < FN; ++n)
                    acc[m][n] = __builtin_amdgcn_mfma_f32_16x16x32_bf16(af[m], bfr[n], acc[m][n], 0, 0, 0);
        }
        __builtin_amdgcn_sched_barrier(0);
        __builtin_amdgcn_s_barrier();
        __builtin_amdgcn_sched_barrier(0);
        cur = (cur + 1 == DEPTH) ? 0 : cur + 1;
    }

    int cl = lane & 15, rq = lane >> 4;
    #pragma unroll
    for (int m = 0; m < FM; ++m) {
        #pragma unroll
        for (int n = 0; n < FN; ++n) {
            int col = col_base + wn*(BN/WC) + n*16 + cl;
            float bv = bias[col];
            float gv = (EPI == 1) ? gvec[col] : 0.f;
            #pragma unroll
            for (int j = 0; j < 4; ++j) {
                int row = row_base + wm*(BM/WR) + m*16 + rq*4 + j;
                float v = acc[m][n][j] + bv;
                size_t idx = (size_t)row * N + col;
                if constexpr (EPI == 0) {
                    out[idx] = (OutT)f2bf(v);
                } else if constexpr (EPI == 1) {
                    out[idx] = resid[idx] + gv * v;
                } else { // gelu: 0.5v(1+tanh(u)) == v * sigmoid(2u)
                    float u = 0.7978845608028654f * (v + 0.044715f * v * v * v);
                    out[idx] = (OutT)f2bf(v / (1.f + __expf(-2.f * u)));
                }
            }
        }
    }
}

// ---------------------------------------------------------------------------
// Kernel 4: NATTEN 7x7 — MFMA-tiled. One block per (8x8 query tile, head).
// Window union = 14x14 = 196 keys. K and V staged row-per-key (128B,
// XOR-swizzled via pre-swizzled global source). Swapped-QK^T softmax
// (lane-local); PV B-frags gathered with scalar LDS reads (no tr_read).
// LDS: Q 8K | K 28K | V 28K | P 29K = 93K  (1 block/CU)
// ---------------------------------------------------------------------------
#define QOFF 0
#define KOFF 8192
#define VOFF 36864
#define POFF 65536

__global__ __launch_bounds__(256) void natten_k(const bf16* __restrict__ qkv,
                                                bf16* __restrict__ o)
{
    __shared__ __align__(16) char lds[95232];
    int tid = threadIdx.x;
    int wid = tid >> 6, lane = tid & 63;
    int b = blockIdx.x;
    int h = b % NHD, tile = b / NHD;
    int R0 = (tile >> 3) << 3, C0 = (tile & 7) << 3;
    int wr0 = min(max(R0 - 3, 0), GH - 14);
    int wc0 = min(max(C0 - 3, 0), GW - 14);

    int l8 = lane >> 3, c8 = lane & 7;
    int cs = ((c8 ^ l8) << 3);              // pre-swizzled chunk (elems)

    // ---- stage Q (64 rows x 128B, swizzled) ----
    #pragma unroll
    for (int p = 0; p < 2; ++p) {
        int rb = p * 32 + wid * 8;
        int q  = rb + l8;
        int token = (R0 + (q >> 3)) * GW + C0 + (q & 7);
        __builtin_amdgcn_global_load_lds(
            (gptr_t)(const void*)(qkv + (size_t)token * (3*CC) + h * DH + cs),
            (lptr_t)(void*)(lds + QOFF + rb * 128), 16, 0, 0);
    }
    // ---- stage K and V windows (196 rows x 128B each, swizzled) ----
    #pragma unroll
    for (int p = 0; p < 7; ++p) {
        int rb = p * 32 + wid * 8;
        int key = rb + l8;
        if (key < 196) {
            int kr = (key * 586) >> 13;     // key / 14
            int kc = key - 14 * kr;
            int token = (wr0 + kr) * GW + wc0 + kc;
            const bf16* base = qkv + (size_t)token * (3*CC) + h * DH + cs;
            __builtin_amdgcn_global_load_lds(
                (gptr_t)(const void*)(base + CC),
                (lptr_t)(void*)(lds + KOFF + rb * 128), 16, 0, 0);
            __builtin_amdgcn_global_load_lds(
                (gptr_t)(const void*)(base + 2*CC),
                (lptr_t)(void*)(lds + VOFF + rb * 128), 16, 0, 0);
        }
    }
    // zero V rows 196..223 (28 x 128B = 896 dwords) — killed by P=0, but must
    // not be Inf/NaN
    for (int i = tid; i < 896; i += 256)
        *(unsigned int*)(lds + VOFF + 196*128 + i * 4) = 0u;
    // zero P pad: keys 196..231 of all 64 rows (18 dwords per row)
    for (int i = tid; i < 64*18; i += 256) {
        int row = i / 18, seg = i % 18;
        *(unsigned int*)(lds + POFF + row * 464 + 392 + seg * 4) = 0u;
    }
    __syncthreads();

    // ---- scores: S^T[key][q] = mfma(K, Q), wave w owns q-rows w*16.. ----
    int qme = wid * 16 + (lane & 15);       // this lane's query
    int qr = R0 + (qme >> 3), qc = C0 + (qme & 7);
    int sh = min(max(qr - 3, 0), GH - KW);
    int sw = min(max(qc - 3, 0), GW - KW);

    bf16x8 bq[2];
    #pragma unroll
    for (int kk = 0; kk < 2; ++kk)
        bq[kk] = *(const bf16x8*)(lds + QOFF + qme * 128 +
                  ((kk * 64 + (lane >> 4) * 16) ^ ((qme & 7) << 4)));

    f32x4 sc[13] = {};
    #pragma unroll
    for (int m = 0; m < 13; ++m) {
        #pragma unroll
        for (int kk = 0; kk < 2; ++kk) {
            int R = m * 16 + (lane & 15);
            bf16x8 af = *(const bf16x8*)(lds + KOFF + R * 128 +
                         ((kk * 64 + (lane >> 4) * 16) ^ ((R & 7) << 4)));
            sc[m] = __builtin_amdgcn_mfma_f32_16x16x32_bf16(af, bq[kk], sc[m], 0, 0, 0);
        }
    }
    // ---- mask + softmax (lane-local over 52 vals + 2 shuffles) ----
    float mx = -3e38f;
    #pragma unroll
    for (int m = 0; m < 13; ++m) {
        #pragma unroll
        for (int j = 0; j < 4; ++j) {
            int key = m * 16 + (lane >> 4) * 4 + j;
            int kr = (key * 586) >> 13;
            int kc = key - 14 * kr;
            int kg = wr0 + kr, cg = wc0 + kc;
            bool val = (kg >= sh) && (kg <= sh + 6) && (cg >= sw) && (cg <= sw + 6);
            float s = val ? sc[m][j] * 0.125f : -3e38f;
            sc[m][j] = s;
            mx = fmaxf(mx, s);
        }
    }
    mx = fmaxf(mx, __shfl_xor(mx, 16));
    mx = fmaxf(mx, __shfl_xor(mx, 32));
    float sum = 0.f;
    #pragma unroll
    for (int m = 0; m < 13; ++m)
        #pragma unroll
        for (int j = 0; j < 4; ++j) {
            float e = __expf(sc[m][j] - mx);
            sc[m][j] = e;
            sum += e;
        }
    sum += __shfl_xor(sum, 16);
    sum += __shfl_xor(sum, 32);
    float inv = 1.f / sum;

    // ---- write P (unnormalized) to LDS rows [64][232] bf16 (wave-private) --
    #pragma unroll
    for (int m = 0; m < 13; ++m)
        #pragma unroll
        for (int j = 0; j < 4; ++j) {
            int key = m * 16 + (lane >> 4) * 4 + j;
            *(bf16*)(lds + POFF + qme * 464 + key * 2) = f2bf(sc[m][j]);
        }
    asm volatile("s_waitcnt lgkmcnt(0)" ::: "memory");
    __builtin_amdgcn_sched_barrier(0);

    // ---- PV: O[q][d] = P @ V ; B-frag via scalar swizzled LDS reads ----
    f32x4 oacc[4] = {};
    #pragma unroll
    for (int kk = 0; kk < 7; ++kk) {
        bf16x8 af = *(const bf16x8*)(lds + POFF + qme * 464 + kk * 64 + (lane >> 4) * 16);
        #pragma unroll
        for (int n = 0; n < 4; ++n) {
            int dd = n * 16 + (lane & 15);
            int gch = dd >> 3, dby = (dd & 7) * 2;
            bf16x8 bv;
            #pragma unroll
            for (int j = 0; j < 8; ++j) {
                int key = kk * 32 + (lane >> 4) * 8 + j;
                ((short*)&bv)[j] = *(const short*)(lds + VOFF + key * 128 +
                                    ((gch ^ (key & 7)) << 4) + dby);
            }
            oacc[n] = __builtin_amdgcn_mfma_f32_16x16x32_bf16(af, bv, oacc[n], 0, 0, 0);
        }
    }

    // ---- store: q = wid*16 + (lane>>4)*4 + j, d = n*16 + (lane&15) ----
    #pragma unroll
    for (int j = 0; j < 4; ++j) {
        int idxq = ((lane >> 4) << 2) + j;
        float iv = __shfl(inv, (lane & 48) | idxq);
        int q2 = wid * 16 + idxq;
        int token = (R0 + (q2 >> 3)) * GW + C0 + (q2 & 7);
        #pragma unroll
        for (int n = 0; n < 4; ++n) {
            int d = n * 16 + (lane & 15);
            o[(size_t)token * CC + h * DH + d] = f2bf(oacc[n][j] * iv);
        }
    }
}

// ---------------------------------------------------------------------------
// launch
// ---------------------------------------------------------------------------
extern "C" void kernel_launch(void* const* d_in, const int* in_sizes, int n_in,
                              void* d_out, int out_size, void* d_ws, size_t ws_size,
                              hipStream_t stream)
{
    const float* x      = (const float*)d_in[0];
    const float* cond   = (const float*)d_in[1];
    const float* qkv_w  = (const float*)d_in[2];
    const float* qkv_b  = (const float*)d_in[3];
    const float* proj_w = (const float*)d_in[4];
    const float* proj_b = (const float*)d_in[5];
    const float* fc1_w  = (const float*)d_in[6];
    const float* fc1_b  = (const float*)d_in[7];
    const float* fc2_w  = (const float*)d_in[8];
    const float* fc2_b  = (const float*)d_in[9];
    const float* ada_w  = (const float*)d_in[10];
    const float* ada_b  = (const float*)d_in[11];
    float* out = (float*)d_out;

    char* p = (char*)d_ws;
    float* m       = (float*)p;            p += 6*CC*sizeof(float);
    bf16* y        = (bf16*)p;             p += (size_t)NTOK*CC*2;
    bf16* qkv      = (bf16*)p;             p += (size_t)NTOK*(3*CC)*2;
    bf16* attn_o   = (bf16*)p;             p += (size_t)NTOK*CC*2;
    bf16* hdn      = (bf16*)p;             p += (size_t)NTOK*(4*CC)*2;
    bf16* qkv_wt   = (bf16*)p;             p += (size_t)(3*CC)*CC*2;
    bf16* proj_wt  = (bf16*)p;             p += (size_t)CC*CC*2;
    bf16* fc1_wt   = (bf16*)p;             p += (size_t)(4*CC)*CC*2;
    bf16* fc2_wt   = (bf16*)p;             p += (size_t)CC*(4*CC)*2;

    const float* sh_a = m;
    const float* sc_a = m + CC;
    const float* g_a  = m + 2*CC;
    const float* sh_m = m + 3*CC;
    const float* sc_m = m + 4*CC;
    const float* g_m  = m + 5*CC;

    wt_ada_k<<<468, 256, 0, stream>>>(qkv_w, proj_w, fc1_w, fc2_w,
                                      qkv_wt, proj_wt, fc1_wt, fc2_wt,
                                      cond, ada_w, ada_b, m);
    ln_mod_k<<<NTOK, 128, 0, stream>>>(x, sh_a, sc_a, y);
    mgemm_k<0, bf16, 128, 128, 512, 2><<<dim3((3*CC)/128, NTOK/128), 512, 0, stream>>>(
        y, qkv_wt, qkv_b, nullptr, nullptr, qkv, NTOK, 3*CC, CC);
    natten_k<<<(NTOK/64)*NHD, 256, 0, stream>>>(qkv, attn_o);
    mgemm_k<1, float, 64, 64, 256, 3><<<dim3(CC/64, NTOK/64), 256, 0, stream>>>(
        attn_o, proj_wt, proj_b, x, g_a, out, NTOK, CC, CC);
    ln_mod_k<<<NTOK, 128, 0, stream>>>(out, sh_m, sc_m, y);
    mgemm_k<2, bf16, 128, 128, 512, 2><<<dim3((4*CC)/128, NTOK/128), 512, 0, stream>>>(
        y, fc1_wt, fc1_b, nullptr, nullptr, hdn, NTOK, 4*CC, CC);
    mgemm_k<1, float, 64, 64, 256, 3><<<dim3(CC/64, NTOK/64), 256, 0, stream>>>(
        hdn, fc2_wt, fc2_b, out, g_m, out, NTOK, CC, 4*CC);
}

// Round 11
// 79.923 us; speedup vs baseline: 2.4040x; 1.0856x over previous
//
#include <hip/hip_runtime.h>
#include <hip/hip_bf16.h>
#include <math.h>

// Problem constants
#define GH 64
#define GW 64
#define CC 384
#define NHD 6
#define KW 7
#define DH 64
#define NTOK (GH*GW)          // 4096
#define LN_EPS 1e-6f

typedef __attribute__((ext_vector_type(4))) float f32x4;
typedef __attribute__((ext_vector_type(8))) short bf16x8;
typedef __hip_bfloat16 bf16;

typedef const __attribute__((address_space(1))) unsigned int* gptr_t;
typedef __attribute__((address_space(3))) unsigned int* lptr_t;

__device__ __forceinline__ float bf2f(unsigned int u16) {
    union { unsigned int i; float f; } c; c.i = u16 << 16; return c.f;
}
__device__ __forceinline__ bf16 f2bf(float f) { return __float2bfloat16(f); }

// ---------------------------------------------------------------------------
// Kernel 1: fused {4 weight transposes (64x64 tiles, vectorized)} + {ada}.
// ---------------------------------------------------------------------------
__global__ __launch_bounds__(256) void wt_ada_k(const float* __restrict__ qkv_w,
                                                const float* __restrict__ proj_w,
                                                const float* __restrict__ fc1_w,
                                                const float* __restrict__ fc2_w,
                                                bf16* __restrict__ qkv_wt,
                                                bf16* __restrict__ proj_wt,
                                                bf16* __restrict__ fc1_wt,
                                                bf16* __restrict__ fc2_wt,
                                                const float* __restrict__ cond,
                                                const float* __restrict__ aw,
                                                const float* __restrict__ ab,
                                                float* __restrict__ m)
{
    int b = blockIdx.x;
    int tid = threadIdx.x;
    if (b >= 432) {
        __shared__ float s[CC];
        __shared__ float red[4][64];
        for (int i = tid; i < CC; i += 256) {
            float c = cond[i];
            s[i] = c / (1.f + __expf(-c));
        }
        __syncthreads();
        int c  = tid & 63;
        int ks = tid >> 6;
        int col = (b - 432) * 64 + c;
        float acc = 0.f;
        for (int k = ks * 96; k < (ks + 1) * 96; ++k)
            acc += s[k] * aw[(size_t)k * (6*CC) + col];
        red[ks][c] = acc;
        __syncthreads();
        if (tid < 64)
            m[col] = red[0][c] + red[1][c] + red[2][c] + red[3][c] + ab[col];
        return;
    }
    __shared__ float t[64][65];
    const float* in; bf16* outp; int K, N, lid;
    if (b < 108)       { in = qkv_w;  outp = qkv_wt;  K = 384;  N = 1152; lid = b; }
    else if (b < 144)  { in = proj_w; outp = proj_wt; K = 384;  N = 384;  lid = b - 108; }
    else if (b < 288)  { in = fc1_w;  outp = fc1_wt;  K = 384;  N = 1536; lid = b - 144; }
    else               { in = fc2_w;  outp = fc2_wt;  K = 1536; N = 384;  lid = b - 288; }
    int nbn = N >> 6;
    int bn = (lid % nbn) << 6, bk = (lid / nbn) << 6;
    int c4 = (tid & 15) * 4, r0 = tid >> 4;
    #pragma unroll
    for (int p = 0; p < 4; ++p) {
        int r = r0 + p * 16;
        float4 v = *(const float4*)&in[(size_t)(bk + r) * N + bn + c4];
        t[r][c4+0] = v.x; t[r][c4+1] = v.y; t[r][c4+2] = v.z; t[r][c4+3] = v.w;
    }
    __syncthreads();
    #pragma unroll
    for (int p = 0; p < 4; ++p) {
        int n = r0 + p * 16;
        ushort4 w;
        w.x = __bfloat16_as_ushort(f2bf(t[c4+0][n]));
        w.y = __bfloat16_as_ushort(f2bf(t[c4+1][n]));
        w.z = __bfloat16_as_ushort(f2bf(t[c4+2][n]));
        w.w = __bfloat16_as_ushort(f2bf(t[c4+3][n]));
        *(ushort4*)&outp[(size_t)(bn + n) * K + bk + c4] = w;
    }
}

// ---------------------------------------------------------------------------
// Kernel 2: y = LN(x) * (1 + sc) + sh   -> bf16
// ---------------------------------------------------------------------------
__global__ __launch_bounds__(128) void ln_mod_k(const float* __restrict__ xin,
                                                const float* __restrict__ sh,
                                                const float* __restrict__ sc,
                                                bf16* __restrict__ yout)
{
    int t = blockIdx.x;
    int tid = threadIdx.x;
    const float* xr = xin + (size_t)t * CC;
    float v0 = xr[tid], v1 = xr[tid + 128], v2 = xr[tid + 256];
    float s  = v0 + v1 + v2;
    float ss = v0*v0 + v1*v1 + v2*v2;
    #pragma unroll
    for (int off = 32; off; off >>= 1) {
        s  += __shfl_down(s,  off);
        ss += __shfl_down(ss, off);
    }
    __shared__ float red[4];
    int wid = tid >> 6;
    if ((tid & 63) == 0) { red[wid*2] = s; red[wid*2+1] = ss; }
    __syncthreads();
    s  = red[0] + red[2];
    ss = red[1] + red[3];
    float mean = s * (1.f / CC);
    float var  = ss * (1.f / CC) - mean * mean;
    float rstd = rsqrtf(var + LN_EPS);
    bf16* yr = yout + (size_t)t * CC;
    yr[tid      ] = f2bf((v0 - mean) * rstd * (1.f + sc[tid      ]) + sh[tid      ]);
    yr[tid + 128] = f2bf((v1 - mean) * rstd * (1.f + sc[tid + 128]) + sh[tid + 128]);
    yr[tid + 256] = f2bf((v2 - mean) * rstd * (1.f + sc[tid + 256]) + sh[tid + 256]);
}

// ---------------------------------------------------------------------------
// Kernel 3: MFMA bf16 GEMM + LDS-staged VECTORIZED epilogue.
// Staging structure (gload_lds 16B + XOR swizzle + counted-vmcnt DEPTH pipe)
// proven in R6/R8/R10.  Epilogue now: acc -> LDS (reusing stage bufs) ->
// coalesced 16B stores (bf16x8 / float4 + float4 resid+gvec).
// ---------------------------------------------------------------------------
#define GBK 64

template<int EPI, typename OutT, int BM, int BN, int TPB, int DEPTH>
__global__ __launch_bounds__(TPB) void mgemm_k(const bf16* __restrict__ A,
                                               const bf16* __restrict__ Bt,
                                               const float* __restrict__ bias,
                                               const float* __restrict__ resid,
                                               const float* __restrict__ gvec,
                                               OutT* __restrict__ out,
                                               int M, int N, int Kd)
{
    constexpr int WR = 2, WC = TPB / 128;
    constexpr int FM = BM / WR / 16, FN = BN / WC / 16;
    constexpr int RPP = TPB / 8;
    constexpr int PA = BM / RPP, PB = BN / RPP;
    constexpr int LDST = PA + PB;
    constexpr int STAGE_BYTES = DEPTH * (BM + BN) * GBK * 2;
    constexpr int EPI_BYTES = (EPI == 1) ? BM * (BN + 4) * 4 : BM * (BN + 8) * 2;
    constexpr int SMEM = STAGE_BYTES > EPI_BYTES ? STAGE_BYTES : EPI_BYTES;
    __shared__ __align__(16) char smem[SMEM];
    bf16* As = (bf16*)smem;                          // [DEPTH][BM][GBK]
    bf16* Bs = (bf16*)(smem + DEPTH * BM * GBK * 2); // [DEPTH][BN][GBK]

    int tid = threadIdx.x;
    int wid = tid >> 6, lane = tid & 63;
    int wm = wid / WC, wn = wid % WC;

    int gx = gridDim.x;
    int nwg = gx * gridDim.y;
    int bid = blockIdx.y * gx + blockIdx.x;
    int swz = (bid & 7) * (nwg >> 3) + (bid >> 3);
    int bx = swz % gx, by = swz / gx;

    int row_base = by * BM;
    int col_base = bx * BN;

    int l8 = lane >> 3;
    int cs = ((lane & 7) ^ l8) * 8;
    int xr = (lane & 7) << 4;
    int bcol = (lane >> 4) * 16;

    f32x4 acc[FM][FN] = {};
    const int nt = Kd / GBK;

    auto STAGE = [&](int buf, int t) {
        int k0 = t * GBK;
        #pragma unroll
        for (int p = 0; p < PA; ++p) {
            int rb = p * RPP + wid * 8;
            __builtin_amdgcn_global_load_lds(
                (gptr_t)(const void*)(A + (size_t)(row_base + rb + l8) * Kd + k0 + cs),
                (lptr_t)(void*)(As + (buf * BM + rb) * GBK), 16, 0, 0);
        }
        #pragma unroll
        for (int p = 0; p < PB; ++p) {
            int rb = p * RPP + wid * 8;
            __builtin_amdgcn_global_load_lds(
                (gptr_t)(const void*)(Bt + (size_t)(col_base + rb + l8) * Kd + k0 + cs),
                (lptr_t)(void*)(Bs + (buf * BN + rb) * GBK), 16, 0, 0);
        }
    };

    #pragma unroll
    for (int d = 0; d < DEPTH - 1; ++d) STAGE(d, d);

    int cur = 0;
    for (int t = 0; t < nt; ++t) {
        if (t + DEPTH - 1 < nt)
            STAGE((cur + DEPTH - 1) % DEPTH, t + DEPTH - 1);
        int ahead = min(nt - 1, t + DEPTH - 1) - t;
        if constexpr (DEPTH == 3) {
            if (ahead == 2)      asm volatile("s_waitcnt vmcnt(%0)" :: "n"(2*LDST) : "memory");
            else if (ahead == 1) asm volatile("s_waitcnt vmcnt(%0)" :: "n"(LDST)   : "memory");
            else                 asm volatile("s_waitcnt vmcnt(0)" ::: "memory");
        } else {
            if (ahead == 1)      asm volatile("s_waitcnt vmcnt(%0)" :: "n"(LDST)   : "memory");
            else                 asm volatile("s_waitcnt vmcnt(0)" ::: "memory");
        }
        __builtin_amdgcn_sched_barrier(0);
        __builtin_amdgcn_s_barrier();
        __builtin_amdgcn_sched_barrier(0);
        #pragma unroll
        for (int kk = 0; kk < GBK; kk += 32) {
            bf16x8 af[FM], bfr[FN];
            #pragma unroll
            for (int m = 0; m < FM; ++m) {
                int R = wm*(BM/WR) + m*16 + (lane & 15);
                af[m]  = *(const bf16x8*)((const char*)As + (cur*BM + R)*128 + ((kk*2 + bcol) ^ xr));
            }
            #pragma unroll
            for (int n = 0; n < FN; ++n) {
                int R = wn*(BN/WC) + n*16 + (lane & 15);
                bfr[n] = *(const bf16x8*)((const char*)Bs + (cur*BN + R)*128 + ((kk*2 + bcol) ^ xr));
            }
            #pragma unroll
            for (int m = 0; m < FM; ++m)
                #pragma unroll
                for (int n = 0; n < FN; ++n)
                    acc[m][n] = __builtin_amdgcn_mfma_f32_16x16x32_bf16(af[m], bfr[n], acc[m][n], 0, 0, 0);
        }
        __builtin_amdgcn_sched_barrier(0);
        __builtin_amdgcn_s_barrier();
        __builtin_amdgcn_sched_barrier(0);
        cur = (cur + 1 == DEPTH) ? 0 : cur + 1;
    }

    // ---- LDS-staged vectorized epilogue ----
    int cl = lane & 15, rq = lane >> 4;
    if constexpr (EPI == 1) {
        float* et = (float*)smem;                    // [BM][BN+4]
        #pragma unroll
        for (int m = 0; m < FM; ++m)
            #pragma unroll
            for (int n = 0; n < FN; ++n) {
                int col = wn*(BN/WC) + n*16 + cl;
                float bv = bias[col_base + col];
                #pragma unroll
                for (int j = 0; j < 4; ++j) {
                    int row = wm*(BM/WR) + m*16 + rq*4 + j;
                    et[row*(BN+4) + col] = acc[m][n][j] + bv;
                }
            }
        __syncthreads();
        constexpr int CH = BN / 4;
        #pragma unroll
        for (int p = 0; p < (BM*CH)/TPB; ++p) {
            int idx = p * TPB + tid;
            int row = idx / CH, ch = idx % CH;
            float4 v = *(const float4*)&et[row*(BN+4) + ch*4];
            size_t gidx = (size_t)(row_base + row) * N + col_base + ch*4;
            float4 r = *(const float4*)&resid[gidx];
            float4 g = *(const float4*)&gvec[col_base + ch*4];
            float4 o;
            o.x = r.x + g.x * v.x;
            o.y = r.y + g.y * v.y;
            o.z = r.z + g.z * v.z;
            o.w = r.w + g.w * v.w;
            *(float4*)&((float*)out)[gidx] = o;
        }
    } else {
        bf16* et = (bf16*)smem;                      // [BM][BN+8]
        #pragma unroll
        for (int m = 0; m < FM; ++m)
            #pragma unroll
            for (int n = 0; n < FN; ++n) {
                int col = wn*(BN/WC) + n*16 + cl;
                float bv = bias[col_base + col];
                #pragma unroll
                for (int j = 0; j < 4; ++j) {
                    int row = wm*(BM/WR) + m*16 + rq*4 + j;
                    float v = acc[m][n][j] + bv;
                    if constexpr (EPI == 2) {        // gelu = v*sigmoid(2u)
                        float u = 0.7978845608028654f * (v + 0.044715f * v * v * v);
                        v = v / (1.f + __expf(-2.f * u));
                    }
                    et[row*(BN+8) + col] = f2bf(v);
                }
            }
        __syncthreads();
        constexpr int CH = BN / 8;
        #pragma unroll
        for (int p = 0; p < (BM*CH)/TPB; ++p) {
            int idx = p * TPB + tid;
            int row = idx / CH, ch = idx % CH;
            bf16x8 v = *(const bf16x8*)&et[row*(BN+8) + ch*8];
            *(bf16x8*)&((bf16*)out)[(size_t)(row_base + row) * N + col_base + ch*8] = v;
        }
    }
}

// ---------------------------------------------------------------------------
// Kernel 4: NATTEN 7x7 — MFMA-tiled (proven R10, unchanged)
// ---------------------------------------------------------------------------
#define QOFF 0
#define KOFF 8192
#define VOFF 36864
#define POFF 65536

__global__ __launch_bounds__(256) void natten_k(const bf16* __restrict__ qkv,
                                                bf16* __restrict__ o)
{
    __shared__ __align__(16) char lds[95232];
    int tid = threadIdx.x;
    int wid = tid >> 6, lane = tid & 63;
    int b = blockIdx.x;
    int h = b % NHD, tile = b / NHD;
    int R0 = (tile >> 3) << 3, C0 = (tile & 7) << 3;
    int wr0 = min(max(R0 - 3, 0), GH - 14);
    int wc0 = min(max(C0 - 3, 0), GW - 14);

    int l8 = lane >> 3, c8 = lane & 7;
    int cs = ((c8 ^ l8) << 3);

    #pragma unroll
    for (int p = 0; p < 2; ++p) {
        int rb = p * 32 + wid * 8;
        int q  = rb + l8;
        int token = (R0 + (q >> 3)) * GW + C0 + (q & 7);
        __builtin_amdgcn_global_load_lds(
            (gptr_t)(const void*)(qkv + (size_t)token * (3*CC) + h * DH + cs),
            (lptr_t)(void*)(lds + QOFF + rb * 128), 16, 0, 0);
    }
    #pragma unroll
    for (int p = 0; p < 7; ++p) {
        int rb = p * 32 + wid * 8;
        int key = rb + l8;
        if (key < 196) {
            int kr = (key * 586) >> 13;
            int kc = key - 14 * kr;
            int token = (wr0 + kr) * GW + wc0 + kc;
            const bf16* base = qkv + (size_t)token * (3*CC) + h * DH + cs;
            __builtin_amdgcn_global_load_lds(
                (gptr_t)(const void*)(base + CC),
                (lptr_t)(void*)(lds + KOFF + rb * 128), 16, 0, 0);
            __builtin_amdgcn_global_load_lds(
                (gptr_t)(const void*)(base + 2*CC),
                (lptr_t)(void*)(lds + VOFF + rb * 128), 16, 0, 0);
        }
    }
    for (int i = tid; i < 896; i += 256)
        *(unsigned int*)(lds + VOFF + 196*128 + i * 4) = 0u;
    for (int i = tid; i < 64*18; i += 256) {
        int row = i / 18, seg = i % 18;
        *(unsigned int*)(lds + POFF + row * 464 + 392 + seg * 4) = 0u;
    }
    __syncthreads();

    int qme = wid * 16 + (lane & 15);
    int qr = R0 + (qme >> 3), qc = C0 + (qme & 7);
    int sh = min(max(qr - 3, 0), GH - KW);
    int sw = min(max(qc - 3, 0), GW - KW);

    bf16x8 bq[2];
    #pragma unroll
    for (int kk = 0; kk < 2; ++kk)
        bq[kk] = *(const bf16x8*)(lds + QOFF + qme * 128 +
                  ((kk * 64 + (lane >> 4) * 16) ^ ((qme & 7) << 4)));

    f32x4 sc[13] = {};
    #pragma unroll
    for (int m = 0; m < 13; ++m) {
        #pragma unroll
        for (int kk = 0; kk < 2; ++kk) {
            int R = m * 16 + (lane & 15);
            bf16x8 af = *(const bf16x8*)(lds + KOFF + R * 128 +
                         ((kk * 64 + (lane >> 4) * 16) ^ ((R & 7) << 4)));
            sc[m] = __builtin_amdgcn_mfma_f32_16x16x32_bf16(af, bq[kk], sc[m], 0, 0, 0);
        }
    }
    float mx = -3e38f;
    #pragma unroll
    for (int m = 0; m < 13; ++m) {
        #pragma unroll
        for (int j = 0; j < 4; ++j) {
            int key = m * 16 + (lane >> 4) * 4 + j;
            int kr = (key * 586) >> 13;
            int kc = key - 14 * kr;
            int kg = wr0 + kr, cg = wc0 + kc;
            bool val = (kg >= sh) && (kg <= sh + 6) && (cg >= sw) && (cg <= sw + 6);
            float s = val ? sc[m][j] * 0.125f : -3e38f;
            sc[m][j] = s;
            mx = fmaxf(mx, s);
        }
    }
    mx = fmaxf(mx, __shfl_xor(mx, 16));
    mx = fmaxf(mx, __shfl_xor(mx, 32));
    float sum = 0.f;
    #pragma unroll
    for (int m = 0; m < 13; ++m)
        #pragma unroll
        for (int j = 0; j < 4; ++j) {
            float e = __expf(sc[m][j] - mx);
            sc[m][j] = e;
            sum += e;
        }
    sum += __shfl_xor(sum, 16);
    sum += __shfl_xor(sum, 32);
    float inv = 1.f / sum;

    #pragma unroll
    for (int m = 0; m < 13; ++m)
        #pragma unroll
        for (int j = 0; j < 4; ++j) {
            int key = m * 16 + (lane >> 4) * 4 + j;
            *(bf16*)(lds + POFF + qme * 464 + key * 2) = f2bf(sc[m][j]);
        }
    asm volatile("s_waitcnt lgkmcnt(0)" ::: "memory");
    __builtin_amdgcn_sched_barrier(0);

    f32x4 oacc[4] = {};
    #pragma unroll
    for (int kk = 0; kk < 7; ++kk) {
        bf16x8 af = *(const bf16x8*)(lds + POFF + qme * 464 + kk * 64 + (lane >> 4) * 16);
        #pragma unroll
        for (int n = 0; n < 4; ++n) {
            int dd = n * 16 + (lane & 15);
            int gch = dd >> 3, dby = (dd & 7) * 2;
            bf16x8 bv;
            #pragma unroll
            for (int j = 0; j < 8; ++j) {
                int key = kk * 32 + (lane >> 4) * 8 + j;
                ((short*)&bv)[j] = *(const short*)(lds + VOFF + key * 128 +
                                    ((gch ^ (key & 7)) << 4) + dby);
            }
            oacc[n] = __builtin_amdgcn_mfma_f32_16x16x32_bf16(af, bv, oacc[n], 0, 0, 0);
        }
    }

    #pragma unroll
    for (int j = 0; j < 4; ++j) {
        int idxq = ((lane >> 4) << 2) + j;
        float iv = __shfl(inv, (lane & 48) | idxq);
        int q2 = wid * 16 + idxq;
        int token = (R0 + (q2 >> 3)) * GW + C0 + (q2 & 7);
        #pragma unroll
        for (int n = 0; n < 4; ++n) {
            int d = n * 16 + (lane & 15);
            o[(size_t)token * CC + h * DH + d] = f2bf(oacc[n][j] * iv);
        }
    }
}

// ---------------------------------------------------------------------------
// launch
// ---------------------------------------------------------------------------
extern "C" void kernel_launch(void* const* d_in, const int* in_sizes, int n_in,
                              void* d_out, int out_size, void* d_ws, size_t ws_size,
                              hipStream_t stream)
{
    const float* x      = (const float*)d_in[0];
    const float* cond   = (const float*)d_in[1];
    const float* qkv_w  = (const float*)d_in[2];
    const float* qkv_b  = (const float*)d_in[3];
    const float* proj_w = (const float*)d_in[4];
    const float* proj_b = (const float*)d_in[5];
    const float* fc1_w  = (const float*)d_in[6];
    const float* fc1_b  = (const float*)d_in[7];
    const float* fc2_w  = (const float*)d_in[8];
    const float* fc2_b  = (const float*)d_in[9];
    const float* ada_w  = (const float*)d_in[10];
    const float* ada_b  = (const float*)d_in[11];
    float* out = (float*)d_out;

    char* p = (char*)d_ws;
    float* m       = (float*)p;            p += 6*CC*sizeof(float);
    bf16* y        = (bf16*)p;             p += (size_t)NTOK*CC*2;
    bf16* qkv      = (bf16*)p;             p += (size_t)NTOK*(3*CC)*2;
    bf16* attn_o   = (bf16*)p;             p += (size_t)NTOK*CC*2;
    bf16* hdn      = (bf16*)p;             p += (size_t)NTOK*(4*CC)*2;
    bf16* qkv_wt   = (bf16*)p;             p += (size_t)(3*CC)*CC*2;
    bf16* proj_wt  = (bf16*)p;             p += (size_t)CC*CC*2;
    bf16* fc1_wt   = (bf16*)p;             p += (size_t)(4*CC)*CC*2;
    bf16* fc2_wt   = (bf16*)p;             p += (size_t)CC*(4*CC)*2;

    const float* sh_a = m;
    const float* sc_a = m + CC;
    const float* g_a  = m + 2*CC;
    const float* sh_m = m + 3*CC;
    const float* sc_m = m + 4*CC;
    const float* g_m  = m + 5*CC;

    wt_ada_k<<<468, 256, 0, stream>>>(qkv_w, proj_w, fc1_w, fc2_w,
                                      qkv_wt, proj_wt, fc1_wt, fc2_wt,
                                      cond, ada_w, ada_b, m);
    ln_mod_k<<<NTOK, 128, 0, stream>>>(x, sh_a, sc_a, y);
    mgemm_k<0, bf16, 128, 128, 512, 2><<<dim3((3*CC)/128, NTOK/128), 512, 0, stream>>>(
        y, qkv_wt, qkv_b, nullptr, nullptr, qkv, NTOK, 3*CC, CC);
    natten_k<<<(NTOK/64)*NHD, 256, 0, stream>>>(qkv, attn_o);
    mgemm_k<1, float, 64, 64, 256, 3><<<dim3(CC/64, NTOK/64), 256, 0, stream>>>(
        attn_o, proj_wt, proj_b, x, g_a, out, NTOK, CC, CC);
    ln_mod_k<<<NTOK, 128, 0, stream>>>(out, sh_m, sc_m, y);
    mgemm_k<2, bf16, 128, 128, 512, 2><<<dim3((4*CC)/128, NTOK/128), 512, 0, stream>>>(
        y, fc1_wt, fc1_b, nullptr, nullptr, hdn, NTOK, 4*CC, CC);
    mgemm_k<1, float, 64, 64, 256, 3><<<dim3(CC/64, NTOK/64), 256, 0, stream>>>(
        hdn, fc2_wt, fc2_b, out, g_m, out, NTOK, CC, 4*CC);
}

// Round 12
// 79.840 us; speedup vs baseline: 2.4065x; 1.0010x over previous
//
#include <hip/hip_runtime.h>
#include <hip/hip_bf16.h>
#include <math.h>

// Problem constants
#define GH 64
#define GW 64
#define CC 384
#define NHD 6
#define KW 7
#define DH 64
#define NTOK (GH*GW)          // 4096
#define LN_EPS 1e-6f

typedef __attribute__((ext_vector_type(4))) float f32x4;
typedef __attribute__((ext_vector_type(8))) short bf16x8;
typedef __hip_bfloat16 bf16;

typedef const __attribute__((address_space(1))) unsigned int* gptr_t;
typedef __attribute__((address_space(3))) unsigned int* lptr_t;

__device__ __forceinline__ float bf2f(unsigned int u16) {
    union { unsigned int i; float f; } c; c.i = u16 << 16; return c.f;
}
__device__ __forceinline__ bf16 f2bf(float f) { return __float2bfloat16(f); }

// ---------------------------------------------------------------------------
// Kernel 1: fused {4 weight transposes (64x64 tiles, vectorized)} + {ada}.
// ---------------------------------------------------------------------------
__global__ __launch_bounds__(256) void wt_ada_k(const float* __restrict__ qkv_w,
                                                const float* __restrict__ proj_w,
                                                const float* __restrict__ fc1_w,
                                                const float* __restrict__ fc2_w,
                                                bf16* __restrict__ qkv_wt,
                                                bf16* __restrict__ proj_wt,
                                                bf16* __restrict__ fc1_wt,
                                                bf16* __restrict__ fc2_wt,
                                                const float* __restrict__ cond,
                                                const float* __restrict__ aw,
                                                const float* __restrict__ ab,
                                                float* __restrict__ m)
{
    int b = blockIdx.x;
    int tid = threadIdx.x;
    if (b >= 432) {
        __shared__ float s[CC];
        __shared__ float red[4][64];
        for (int i = tid; i < CC; i += 256) {
            float c = cond[i];
            s[i] = c / (1.f + __expf(-c));
        }
        __syncthreads();
        int c  = tid & 63;
        int ks = tid >> 6;
        int col = (b - 432) * 64 + c;
        float acc = 0.f;
        for (int k = ks * 96; k < (ks + 1) * 96; ++k)
            acc += s[k] * aw[(size_t)k * (6*CC) + col];
        red[ks][c] = acc;
        __syncthreads();
        if (tid < 64)
            m[col] = red[0][c] + red[1][c] + red[2][c] + red[3][c] + ab[col];
        return;
    }
    __shared__ float t[64][65];
    const float* in; bf16* outp; int K, N, lid;
    if (b < 108)       { in = qkv_w;  outp = qkv_wt;  K = 384;  N = 1152; lid = b; }
    else if (b < 144)  { in = proj_w; outp = proj_wt; K = 384;  N = 384;  lid = b - 108; }
    else if (b < 288)  { in = fc1_w;  outp = fc1_wt;  K = 384;  N = 1536; lid = b - 144; }
    else               { in = fc2_w;  outp = fc2_wt;  K = 1536; N = 384;  lid = b - 288; }
    int nbn = N >> 6;
    int bn = (lid % nbn) << 6, bk = (lid / nbn) << 6;
    int c4 = (tid & 15) * 4, r0 = tid >> 4;
    #pragma unroll
    for (int p = 0; p < 4; ++p) {
        int r = r0 + p * 16;
        float4 v = *(const float4*)&in[(size_t)(bk + r) * N + bn + c4];
        t[r][c4+0] = v.x; t[r][c4+1] = v.y; t[r][c4+2] = v.z; t[r][c4+3] = v.w;
    }
    __syncthreads();
    #pragma unroll
    for (int p = 0; p < 4; ++p) {
        int n = r0 + p * 16;
        ushort4 w;
        w.x = __bfloat16_as_ushort(f2bf(t[c4+0][n]));
        w.y = __bfloat16_as_ushort(f2bf(t[c4+1][n]));
        w.z = __bfloat16_as_ushort(f2bf(t[c4+2][n]));
        w.w = __bfloat16_as_ushort(f2bf(t[c4+3][n]));
        *(ushort4*)&outp[(size_t)(bn + n) * K + bk + c4] = w;
    }
}

// ---------------------------------------------------------------------------
// Kernel 2: y = LN(x) * (1 + sc) + sh   -> bf16
// ---------------------------------------------------------------------------
__global__ __launch_bounds__(128) void ln_mod_k(const float* __restrict__ xin,
                                                const float* __restrict__ sh,
                                                const float* __restrict__ sc,
                                                bf16* __restrict__ yout)
{
    int t = blockIdx.x;
    int tid = threadIdx.x;
    const float* xr = xin + (size_t)t * CC;
    float v0 = xr[tid], v1 = xr[tid + 128], v2 = xr[tid + 256];
    float s  = v0 + v1 + v2;
    float ss = v0*v0 + v1*v1 + v2*v2;
    #pragma unroll
    for (int off = 32; off; off >>= 1) {
        s  += __shfl_down(s,  off);
        ss += __shfl_down(ss, off);
    }
    __shared__ float red[4];
    int wid = tid >> 6;
    if ((tid & 63) == 0) { red[wid*2] = s; red[wid*2+1] = ss; }
    __syncthreads();
    s  = red[0] + red[2];
    ss = red[1] + red[3];
    float mean = s * (1.f / CC);
    float var  = ss * (1.f / CC) - mean * mean;
    float rstd = rsqrtf(var + LN_EPS);
    bf16* yr = yout + (size_t)t * CC;
    yr[tid      ] = f2bf((v0 - mean) * rstd * (1.f + sc[tid      ]) + sh[tid      ]);
    yr[tid + 128] = f2bf((v1 - mean) * rstd * (1.f + sc[tid + 128]) + sh[tid + 128]);
    yr[tid + 256] = f2bf((v2 - mean) * rstd * (1.f + sc[tid + 256]) + sh[tid + 256]);
}

// ---------------------------------------------------------------------------
// Kernel 3: MFMA bf16 GEMM, gload_lds(16B) + XOR swizzle + counted-vmcnt
// DEPTH pipeline + LDS-staged vectorized epilogue (all proven R5-R11).
// This round: occupancy-sized tiles (>=2.25 blocks/CU on every shape).
// ---------------------------------------------------------------------------
#define GBK 64

template<int EPI, typename OutT, int BM, int BN, int TPB, int DEPTH>
__global__ __launch_bounds__(TPB) void mgemm_k(const bf16* __restrict__ A,
                                               const bf16* __restrict__ Bt,
                                               const float* __restrict__ bias,
                                               const float* __restrict__ resid,
                                               const float* __restrict__ gvec,
                                               OutT* __restrict__ out,
                                               int M, int N, int Kd)
{
    constexpr int WR = 2, WC = TPB / 128;
    constexpr int FM = BM / WR / 16, FN = BN / WC / 16;
    constexpr int RPP = TPB / 8;
    constexpr int PA = BM / RPP > 0 ? BM / RPP : 1;
    constexpr int PB = BN / RPP > 0 ? BN / RPP : 1;
    constexpr int LDST = PA + PB;
    constexpr int STAGE_BYTES = DEPTH * (BM + BN) * GBK * 2;
    constexpr int EPI_BYTES = (EPI == 1) ? BM * (BN + 4) * 4 : BM * (BN + 8) * 2;
    constexpr int SMEM = STAGE_BYTES > EPI_BYTES ? STAGE_BYTES : EPI_BYTES;
    __shared__ __align__(16) char smem[SMEM];
    bf16* As = (bf16*)smem;                          // [DEPTH][BM][GBK]
    bf16* Bs = (bf16*)(smem + DEPTH * BM * GBK * 2); // [DEPTH][BN][GBK]

    int tid = threadIdx.x;
    int wid = tid >> 6, lane = tid & 63;
    int wm = wid / WC, wn = wid % WC;

    int gx = gridDim.x;
    int nwg = gx * gridDim.y;
    int bid = blockIdx.y * gx + blockIdx.x;
    int swz = (bid & 7) * (nwg >> 3) + (bid >> 3);
    int bx = swz % gx, by = swz / gx;

    int row_base = by * BM;
    int col_base = bx * BN;

    int l8 = lane >> 3;
    int cs = ((lane & 7) ^ l8) * 8;
    int xr = (lane & 7) << 4;
    int bcol = (lane >> 4) * 16;

    f32x4 acc[FM][FN] = {};
    const int nt = Kd / GBK;

    auto STAGE = [&](int buf, int t) {
        int k0 = t * GBK;
        #pragma unroll
        for (int p = 0; p < PA; ++p) {
            int rb = (p * RPP + wid * 8) % BM;
            __builtin_amdgcn_global_load_lds(
                (gptr_t)(const void*)(A + (size_t)(row_base + rb + l8) * Kd + k0 + cs),
                (lptr_t)(void*)(As + (buf * BM + rb) * GBK), 16, 0, 0);
        }
        #pragma unroll
        for (int p = 0; p < PB; ++p) {
            int rb = (p * RPP + wid * 8) % BN;
            __builtin_amdgcn_global_load_lds(
                (gptr_t)(const void*)(Bt + (size_t)(col_base + rb + l8) * Kd + k0 + cs),
                (lptr_t)(void*)(Bs + (buf * BN + rb) * GBK), 16, 0, 0);
        }
    };

    #pragma unroll
    for (int d = 0; d < DEPTH - 1; ++d) STAGE(d, d);

    int cur = 0;
    for (int t = 0; t < nt; ++t) {
        if (t + DEPTH - 1 < nt)
            STAGE((cur + DEPTH - 1) % DEPTH, t + DEPTH - 1);
        int ahead = min(nt - 1, t + DEPTH - 1) - t;
        if constexpr (DEPTH == 3) {
            if (ahead == 2)      asm volatile("s_waitcnt vmcnt(%0)" :: "n"(2*LDST) : "memory");
            else if (ahead == 1) asm volatile("s_waitcnt vmcnt(%0)" :: "n"(LDST)   : "memory");
            else                 asm volatile("s_waitcnt vmcnt(0)" ::: "memory");
        } else {
            if (ahead == 1)      asm volatile("s_waitcnt vmcnt(%0)" :: "n"(LDST)   : "memory");
            else                 asm volatile("s_waitcnt vmcnt(0)" ::: "memory");
        }
        __builtin_amdgcn_sched_barrier(0);
        __builtin_amdgcn_s_barrier();
        __builtin_amdgcn_sched_barrier(0);
        #pragma unroll
        for (int kk = 0; kk < GBK; kk += 32) {
            bf16x8 af[FM], bfr[FN];
            #pragma unroll
            for (int m = 0; m < FM; ++m) {
                int R = wm*(BM/WR) + m*16 + (lane & 15);
                af[m]  = *(const bf16x8*)((const char*)As + (cur*BM + R)*128 + ((kk*2 + bcol) ^ xr));
            }
            #pragma unroll
            for (int n = 0; n < FN; ++n) {
                int R = wn*(BN/WC) + n*16 + (lane & 15);
                bfr[n] = *(const bf16x8*)((const char*)Bs + (cur*BN + R)*128 + ((kk*2 + bcol) ^ xr));
            }
            #pragma unroll
            for (int m = 0; m < FM; ++m)
                #pragma unroll
                for (int n = 0; n < FN; ++n)
                    acc[m][n] = __builtin_amdgcn_mfma_f32_16x16x32_bf16(af[m], bfr[n], acc[m][n], 0, 0, 0);
        }
        __builtin_amdgcn_sched_barrier(0);
        __builtin_amdgcn_s_barrier();
        __builtin_amdgcn_sched_barrier(0);
        cur = (cur + 1 == DEPTH) ? 0 : cur + 1;
    }

    // ---- LDS-staged vectorized epilogue ----
    int cl = lane & 15, rq = lane >> 4;
    if constexpr (EPI == 1) {
        float* et = (float*)smem;                    // [BM][BN+4]
        #pragma unroll
        for (int m = 0; m < FM; ++m)
            #pragma unroll
            for (int n = 0; n < FN; ++n) {
                int col = wn*(BN/WC) + n*16 + cl;
                float bv = bias[col_base + col];
                #pragma unroll
                for (int j = 0; j < 4; ++j) {
                    int row = wm*(BM/WR) + m*16 + rq*4 + j;
                    et[row*(BN+4) + col] = acc[m][n][j] + bv;
                }
            }
        __syncthreads();
        constexpr int CH = BN / 4;
        #pragma unroll
        for (int p = 0; p < (BM*CH)/TPB; ++p) {
            int idx = p * TPB + tid;
            int row = idx / CH, ch = idx % CH;
            float4 v = *(const float4*)&et[row*(BN+4) + ch*4];
            size_t gidx = (size_t)(row_base + row) * N + col_base + ch*4;
            float4 r = *(const float4*)&resid[gidx];
            float4 g = *(const float4*)&gvec[col_base + ch*4];
            float4 o;
            o.x = r.x + g.x * v.x;
            o.y = r.y + g.y * v.y;
            o.z = r.z + g.z * v.z;
            o.w = r.w + g.w * v.w;
            *(float4*)&((float*)out)[gidx] = o;
        }
    } else {
        bf16* et = (bf16*)smem;                      // [BM][BN+8]
        #pragma unroll
        for (int m = 0; m < FM; ++m)
            #pragma unroll
            for (int n = 0; n < FN; ++n) {
                int col = wn*(BN/WC) + n*16 + cl;
                float bv = bias[col_base + col];
                #pragma unroll
                for (int j = 0; j < 4; ++j) {
                    int row = wm*(BM/WR) + m*16 + rq*4 + j;
                    float v = acc[m][n][j] + bv;
                    if constexpr (EPI == 2) {        // gelu = v*sigmoid(2u)
                        float u = 0.7978845608028654f * (v + 0.044715f * v * v * v);
                        v = v / (1.f + __expf(-2.f * u));
                    }
                    et[row*(BN+8) + col] = f2bf(v);
                }
            }
        __syncthreads();
        constexpr int CH = BN / 8;
        #pragma unroll
        for (int p = 0; p < (BM*CH)/TPB; ++p) {
            int idx = p * TPB + tid;
            int row = idx / CH, ch = idx % CH;
            bf16x8 v = *(const bf16x8*)&et[row*(BN+8) + ch*8];
            *(bf16x8*)&((bf16*)out)[(size_t)(row_base + row) * N + col_base + ch*8] = v;
        }
    }
}

// ---------------------------------------------------------------------------
// Kernel 4: NATTEN 7x7 — MFMA-tiled (proven R10, unchanged)
// ---------------------------------------------------------------------------
#define QOFF 0
#define KOFF 8192
#define VOFF 36864
#define POFF 65536

__global__ __launch_bounds__(256) void natten_k(const bf16* __restrict__ qkv,
                                                bf16* __restrict__ o)
{
    __shared__ __align__(16) char lds[95232];
    int tid = threadIdx.x;
    int wid = tid >> 6, lane = tid & 63;
    int b = blockIdx.x;
    int h = b % NHD, tile = b / NHD;
    int R0 = (tile >> 3) << 3, C0 = (tile & 7) << 3;
    int wr0 = min(max(R0 - 3, 0), GH - 14);
    int wc0 = min(max(C0 - 3, 0), GW - 14);

    int l8 = lane >> 3, c8 = lane & 7;
    int cs = ((c8 ^ l8) << 3);

    #pragma unroll
    for (int p = 0; p < 2; ++p) {
        int rb = p * 32 + wid * 8;
        int q  = rb + l8;
        int token = (R0 + (q >> 3)) * GW + C0 + (q & 7);
        __builtin_amdgcn_global_load_lds(
            (gptr_t)(const void*)(qkv + (size_t)token * (3*CC) + h * DH + cs),
            (lptr_t)(void*)(lds + QOFF + rb * 128), 16, 0, 0);
    }
    #pragma unroll
    for (int p = 0; p < 7; ++p) {
        int rb = p * 32 + wid * 8;
        int key = rb + l8;
        if (key < 196) {
            int kr = (key * 586) >> 13;
            int kc = key - 14 * kr;
            int token = (wr0 + kr) * GW + wc0 + kc;
            const bf16* base = qkv + (size_t)token * (3*CC) + h * DH + cs;
            __builtin_amdgcn_global_load_lds(
                (gptr_t)(const void*)(base + CC),
                (lptr_t)(void*)(lds + KOFF + rb * 128), 16, 0, 0);
            __builtin_amdgcn_global_load_lds(
                (gptr_t)(const void*)(base + 2*CC),
                (lptr_t)(void*)(lds + VOFF + rb * 128), 16, 0, 0);
        }
    }
    for (int i = tid; i < 896; i += 256)
        *(unsigned int*)(lds + VOFF + 196*128 + i * 4) = 0u;
    for (int i = tid; i < 64*18; i += 256) {
        int row = i / 18, seg = i % 18;
        *(unsigned int*)(lds + POFF + row * 464 + 392 + seg * 4) = 0u;
    }
    __syncthreads();

    int qme = wid * 16 + (lane & 15);
    int qr = R0 + (qme >> 3), qc = C0 + (qme & 7);
    int sh = min(max(qr - 3, 0), GH - KW);
    int sw = min(max(qc - 3, 0), GW - KW);

    bf16x8 bq[2];
    #pragma unroll
    for (int kk = 0; kk < 2; ++kk)
        bq[kk] = *(const bf16x8*)(lds + QOFF + qme * 128 +
                  ((kk * 64 + (lane >> 4) * 16) ^ ((qme & 7) << 4)));

    f32x4 sc[13] = {};
    #pragma unroll
    for (int m = 0; m < 13; ++m) {
        #pragma unroll
        for (int kk = 0; kk < 2; ++kk) {
            int R = m * 16 + (lane & 15);
            bf16x8 af = *(const bf16x8*)(lds + KOFF + R * 128 +
                         ((kk * 64 + (lane >> 4) * 16) ^ ((R & 7) << 4)));
            sc[m] = __builtin_amdgcn_mfma_f32_16x16x32_bf16(af, bq[kk], sc[m], 0, 0, 0);
        }
    }
    float mx = -3e38f;
    #pragma unroll
    for (int m = 0; m < 13; ++m) {
        #pragma unroll
        for (int j = 0; j < 4; ++j) {
            int key = m * 16 + (lane >> 4) * 4 + j;
            int kr = (key * 586) >> 13;
            int kc = key - 14 * kr;
            int kg = wr0 + kr, cg = wc0 + kc;
            bool val = (kg >= sh) && (kg <= sh + 6) && (cg >= sw) && (cg <= sw + 6);
            float s = val ? sc[m][j] * 0.125f : -3e38f;
            sc[m][j] = s;
            mx = fmaxf(mx, s);
        }
    }
    mx = fmaxf(mx, __shfl_xor(mx, 16));
    mx = fmaxf(mx, __shfl_xor(mx, 32));
    float sum = 0.f;
    #pragma unroll
    for (int m = 0; m < 13; ++m)
        #pragma unroll
        for (int j = 0; j < 4; ++j) {
            float e = __expf(sc[m][j] - mx);
            sc[m][j] = e;
            sum += e;
        }
    sum += __shfl_xor(sum, 16);
    sum += __shfl_xor(sum, 32);
    float inv = 1.f / sum;

    #pragma unroll
    for (int m = 0; m < 13; ++m)
        #pragma unroll
        for (int j = 0; j < 4; ++j) {
            int key = m * 16 + (lane >> 4) * 4 + j;
            *(bf16*)(lds + POFF + qme * 464 + key * 2) = f2bf(sc[m][j]);
        }
    asm volatile("s_waitcnt lgkmcnt(0)" ::: "memory");
    __builtin_amdgcn_sched_barrier(0);

    f32x4 oacc[4] = {};
    #pragma unroll
    for (int kk = 0; kk < 7; ++kk) {
        bf16x8 af = *(const bf16x8*)(lds + POFF + qme * 464 + kk * 64 + (lane >> 4) * 16);
        #pragma unroll
        for (int n = 0; n < 4; ++n) {
            int dd = n * 16 + (lane & 15);
            int gch = dd >> 3, dby = (dd & 7) * 2;
            bf16x8 bv;
            #pragma unroll
            for (int j = 0; j < 8; ++j) {
                int key = kk * 32 + (lane >> 4) * 8 + j;
                ((short*)&bv)[j] = *(const short*)(lds + VOFF + key * 128 +
                                    ((gch ^ (key & 7)) << 4) + dby);
            }
            oacc[n] = __builtin_amdgcn_mfma_f32_16x16x32_bf16(af, bv, oacc[n], 0, 0, 0);
        }
    }

    #pragma unroll
    for (int j = 0; j < 4; ++j) {
        int idxq = ((lane >> 4) << 2) + j;
        float iv = __shfl(inv, (lane & 48) | idxq);
        int q2 = wid * 16 + idxq;
        int token = (R0 + (q2 >> 3)) * GW + C0 + (q2 & 7);
        #pragma unroll
        for (int n = 0; n < 4; ++n) {
            int d = n * 16 + (lane & 15);
            o[(size_t)token * CC + h * DH + d] = f2bf(oacc[n][j] * iv);
        }
    }
}

// ---------------------------------------------------------------------------
// launch
// ---------------------------------------------------------------------------
extern "C" void kernel_launch(void* const* d_in, const int* in_sizes, int n_in,
                              void* d_out, int out_size, void* d_ws, size_t ws_size,
                              hipStream_t stream)
{
    const float* x      = (const float*)d_in[0];
    const float* cond   = (const float*)d_in[1];
    const float* qkv_w  = (const float*)d_in[2];
    const float* qkv_b  = (const float*)d_in[3];
    const float* proj_w = (const float*)d_in[4];
    const float* proj_b = (const float*)d_in[5];
    const float* fc1_w  = (const float*)d_in[6];
    const float* fc1_b  = (const float*)d_in[7];
    const float* fc2_w  = (const float*)d_in[8];
    const float* fc2_b  = (const float*)d_in[9];
    const float* ada_w  = (const float*)d_in[10];
    const float* ada_b  = (const float*)d_in[11];
    float* out = (float*)d_out;

    char* p = (char*)d_ws;
    float* m       = (float*)p;            p += 6*CC*sizeof(float);
    bf16* y        = (bf16*)p;             p += (size_t)NTOK*CC*2;
    bf16* qkv      = (bf16*)p;             p += (size_t)NTOK*(3*CC)*2;
    bf16* attn_o   = (bf16*)p;             p += (size_t)NTOK*CC*2;
    bf16* hdn      = (bf16*)p;             p += (size_t)NTOK*(4*CC)*2;
    bf16* qkv_wt   = (bf16*)p;             p += (size_t)(3*CC)*CC*2;
    bf16* proj_wt  = (bf16*)p;             p += (size_t)CC*CC*2;
    bf16* fc1_wt   = (bf16*)p;             p += (size_t)(4*CC)*CC*2;
    bf16* fc2_wt   = (bf16*)p;             p += (size_t)CC*(4*CC)*2;

    const float* sh_a = m;
    const float* sc_a = m + CC;
    const float* g_a  = m + 2*CC;
    const float* sh_m = m + 3*CC;
    const float* sc_m = m + 4*CC;
    const float* g_m  = m + 5*CC;

    wt_ada_k<<<468, 256, 0, stream>>>(qkv_w, proj_w, fc1_w, fc2_w,
                                      qkv_wt, proj_wt, fc1_wt, fc2_wt,
                                      cond, ada_w, ada_b, m);
    ln_mod_k<<<NTOK, 128, 0, stream>>>(x, sh_a, sc_a, y);
    // qkv: 64x128 tile, grid (9,64)=576 blocks (2.25/CU)
    mgemm_k<0, bf16, 64, 128, 256, 2><<<dim3((3*CC)/128, NTOK/64), 256, 0, stream>>>(
        y, qkv_wt, qkv_b, nullptr, nullptr, qkv, NTOK, 3*CC, CC);
    natten_k<<<(NTOK/64)*NHD, 256, 0, stream>>>(qkv, attn_o);
    // proj: 32x64 tile, depth 3, grid (6,128)=768 blocks (3/CU)
    mgemm_k<1, float, 32, 64, 256, 3><<<dim3(CC/64, NTOK/32), 256, 0, stream>>>(
        attn_o, proj_wt, proj_b, x, g_a, out, NTOK, CC, CC);
    ln_mod_k<<<NTOK, 128, 0, stream>>>(out, sh_m, sc_m, y);
    // fc1: 64x128 tile, grid (12,64)=768 blocks (3/CU)
    mgemm_k<2, bf16, 64, 128, 256, 2><<<dim3((4*CC)/128, NTOK/64), 256, 0, stream>>>(
        y, fc1_wt, fc1_b, nullptr, nullptr, hdn, NTOK, 4*CC, CC);
    // fc2: 32x64 tile, depth 3, grid (6,128)=768 blocks (3/CU), 24 k-iters
    mgemm_k<1, float, 32, 64, 256, 3><<<dim3(CC/64, NTOK/32), 256, 0, stream>>>(
        hdn, fc2_wt, fc2_b, out, g_m, out, NTOK, CC, 4*CC);
}